// Round 6
// baseline (400.530 us; speedup 1.0000x reference)
//
#include <hip/hip_runtime.h>
#include <math.h>

// WaveletAtt: B=2, CIN=DIM=256, HEADS=8, wt_levels=1 Haar
constexpr int B_ = 2;
constexpr int C_ = 256;
constexpr int Hb_ = 128, Wb_ = 128;      // crossFeat / k / v / output spatial
constexpr int Nb_ = Hb_ * Wb_;           // 16384
constexpr int Hs_ = 64, Ws_ = 64;        // x / q spatial
constexpr int Ns_ = Hs_ * Ws_;           // 4096
constexpr int HEADS_ = 8;
constexpr int CHD_ = C_ / HEADS_;        // 32

// ---------------------------------------------------------------------------
// GEMM v3: out[b][o][n] = sum_c W[o][c] * in[b][c][n]
// O-tile 32 (W-slice transposed in LDS, 32 KB), NO X staging, NO main-loop
// barriers: stream in[] coalesced from global (L2/L3-resident), broadcast W
// from LDS, accumulate 32 outputs/thread (x NPT n). c-loop pipelined by 8.
// ---------------------------------------------------------------------------
template<int NTOT>
__global__ __launch_bounds__(256) void gemm_1x1(const float* __restrict__ in,
                                                const float* __restrict__ Wm,
                                                float* __restrict__ out) {
  constexpr int NPT = (NTOT >= 8192) ? 2 : 1;   // n per thread
  __shared__ float Wt[256][32];                 // [c][o_local]
  const int b  = blockIdx.z;
  const int o0 = blockIdx.y * 32;
  const int n0 = blockIdx.x * (256 * NPT);
  const int t  = threadIdx.x;
  // stage Wt (2048 float4): lanes -> consecutive o rows (conflict-free LDS writes)
  for (int i = t; i < 2048; i += 256) {
    int o_l = i & 31, c4 = (i >> 5) << 2;
    float4 w = *(const float4*)(Wm + (size_t)(o0 + o_l) * C_ + c4);
    Wt[c4 + 0][o_l] = w.x; Wt[c4 + 1][o_l] = w.y;
    Wt[c4 + 2][o_l] = w.z; Wt[c4 + 3][o_l] = w.w;
  }
  __syncthreads();
  const float* ip = in + (size_t)b * C_ * NTOT + n0 + t * NPT;
  float acc[32 * NPT] = {};
  float xs[8 * NPT], xc[8 * NPT];
#pragma unroll
  for (int u = 0; u < 8; ++u) {
    if (NPT == 2) {
      float2 v = *(const float2*)&ip[(size_t)u * NTOT];
      xs[2 * u] = v.x; xs[2 * u + 1] = v.y;
    } else {
      xs[u] = ip[(size_t)u * NTOT];
    }
  }
  for (int c0 = 0; c0 < C_; c0 += 8) {
#pragma unroll
    for (int u = 0; u < 8 * NPT; ++u) xc[u] = xs[u];
    if (c0 + 8 < C_) {
#pragma unroll
      for (int u = 0; u < 8; ++u) {
        if (NPT == 2) {
          float2 v = *(const float2*)&ip[(size_t)(c0 + 8 + u) * NTOT];
          xs[2 * u] = v.x; xs[2 * u + 1] = v.y;
        } else {
          xs[u] = ip[(size_t)(c0 + 8 + u) * NTOT];
        }
      }
    }
#pragma unroll
    for (int u = 0; u < 8; ++u) {
#pragma unroll
      for (int g = 0; g < 8; ++g) {
        float4 w = *(float4*)&Wt[c0 + u][g * 4];   // uniform addr -> broadcast
        if (NPT == 2) {
          acc[(g * 4 + 0) * 2]     = fmaf(w.x, xc[2 * u],     acc[(g * 4 + 0) * 2]);
          acc[(g * 4 + 0) * 2 + 1] = fmaf(w.x, xc[2 * u + 1], acc[(g * 4 + 0) * 2 + 1]);
          acc[(g * 4 + 1) * 2]     = fmaf(w.y, xc[2 * u],     acc[(g * 4 + 1) * 2]);
          acc[(g * 4 + 1) * 2 + 1] = fmaf(w.y, xc[2 * u + 1], acc[(g * 4 + 1) * 2 + 1]);
          acc[(g * 4 + 2) * 2]     = fmaf(w.z, xc[2 * u],     acc[(g * 4 + 2) * 2]);
          acc[(g * 4 + 2) * 2 + 1] = fmaf(w.z, xc[2 * u + 1], acc[(g * 4 + 2) * 2 + 1]);
          acc[(g * 4 + 3) * 2]     = fmaf(w.w, xc[2 * u],     acc[(g * 4 + 3) * 2]);
          acc[(g * 4 + 3) * 2 + 1] = fmaf(w.w, xc[2 * u + 1], acc[(g * 4 + 3) * 2 + 1]);
        } else {
          acc[g * 4 + 0] = fmaf(w.x, xc[u], acc[g * 4 + 0]);
          acc[g * 4 + 1] = fmaf(w.y, xc[u], acc[g * 4 + 1]);
          acc[g * 4 + 2] = fmaf(w.z, xc[u], acc[g * 4 + 2]);
          acc[g * 4 + 3] = fmaf(w.w, xc[u], acc[g * 4 + 3]);
        }
      }
    }
  }
  float* op = out + (size_t)b * C_ * NTOT + n0 + t * NPT;
#pragma unroll
  for (int o = 0; o < 32; ++o) {
    if (NPT == 2)
      *(float2*)&op[(size_t)(o0 + o) * NTOT] = make_float2(acc[o * 2], acc[o * 2 + 1]);
    else
      op[(size_t)(o0 + o) * NTOT] = acc[o];
  }
}

// ---------------------------------------------------------------------------
// Fused WTConv (wt_levels=1 Haar): analysis -> dw3x3*scale -> synthesis +
// base dw3x3*base_s, one 64x64 output tile per block, all staged in LDS.
// Staging vectorized: float4 window [ox-4, ox+68) per row, zero outside plane.
// Optional sum(out^2) per (b,c) row into nrm (atomic; zeroed beforehand).
// ---------------------------------------------------------------------------
template<int HP>   // plane is HP x HP (64 or 128)
__global__ __launch_bounds__(256) void wtconv_fused(
    const float* __restrict__ x, const float* __restrict__ bw,
    const float* __restrict__ bs, const float* __restrict__ ww,
    const float* __restrict__ wsc, float* __restrict__ out,
    float* __restrict__ nrm) {
  constexpr int NT = HP / 64;
  const int tile = blockIdx.x;
  const int c = blockIdx.y, b = blockIdx.z;
  const int oy = (tile / NT) * 64, ox = (tile % NT) * 64;
  const float* xp = x + ((size_t)(b * C_) + c) * HP * HP;

  __shared__ float xt[68][76];           // col m <-> gx = ox-4+m (m in 0..71)
  __shared__ float sb[4][34][36];
  __shared__ float red[4];

  float wb[9];
#pragma unroll
  for (int i = 0; i < 9; ++i) wb[i] = bw[c * 9 + i];
  const float sbase = bs[c];
  float wv[4][9]; float sv[4];
#pragma unroll
  for (int f = 0; f < 4; ++f) {
#pragma unroll
    for (int i = 0; i < 9; ++i) wv[f][i] = ww[(c * 4 + f) * 9 + i];
    sv[f] = wsc[c * 4 + f];
  }

  const int t = threadIdx.x;
  // stage 68 rows x 18 float4 (cols [ox-4, ox+68)); aligned, per-float4 bounds
  for (int p = t; p < 68 * 18; p += 256) {
    int r = p / 18, k4 = (p % 18) << 2;
    int gy = oy - 2 + r, gx = ox - 4 + k4;
    float4 v = make_float4(0.f, 0.f, 0.f, 0.f);
    if ((unsigned)gy < (unsigned)HP && (unsigned)gx < (unsigned)HP)
      v = *(const float4*)(xp + (size_t)gy * HP + gx);
    *(float4*)&xt[r][k4] = v;
  }
  __syncthreads();
  // Haar analysis at 34x34 positions; xt col offset +2 vs old layout
  for (int p = t; p < 34 * 34; p += 256) {
    int i = p / 34, j = p % 34;
    float p00 = xt[2 * i][2 * j + 2],     p01 = xt[2 * i][2 * j + 3];
    float p10 = xt[2 * i + 1][2 * j + 2], p11 = xt[2 * i + 1][2 * j + 3];
    sb[0][i][j] = 0.5f * (p00 + p01 + p10 + p11);
    sb[1][i][j] = 0.5f * (p00 + p01 - p10 - p11);
    sb[2][i][j] = 0.5f * (p00 - p01 + p10 - p11);
    sb[3][i][j] = 0.5f * (p00 - p01 - p10 + p11);
  }
  __syncthreads();

  float nacc = 0.f;
  float* op0 = out + ((size_t)(b * C_) + c) * HP * HP;
  for (int p = t; p < 32 * 32; p += 256) {
    int i = p >> 5, j = p & 31;
    float s4[4];
#pragma unroll
    for (int f = 0; f < 4; ++f) {
      float a = 0.f;
#pragma unroll
      for (int dh = 0; dh < 3; ++dh)
#pragma unroll
        for (int dw = 0; dw < 3; ++dw)
          a = fmaf(sb[f][i + dh][j + dw], wv[f][dh * 3 + dw], a);
      s4[f] = a * sv[f];
    }
    float pp[4][4];
#pragma unroll
    for (int r = 0; r < 4; ++r)
#pragma unroll
      for (int cc = 0; cc < 4; ++cc)
        pp[r][cc] = xt[2 * i + 1 + r][2 * j + 3 + cc];
    float o4[2][2];
#pragma unroll
    for (int di = 0; di < 2; ++di)
#pragma unroll
      for (int dj = 0; dj < 2; ++dj) {
        float a = 0.f;
#pragma unroll
        for (int dh = 0; dh < 3; ++dh)
#pragma unroll
          for (int dw = 0; dw < 3; ++dw)
            a = fmaf(pp[di + dh][dj + dw], wb[dh * 3 + dw], a);
        a *= sbase;
        float s1 = di ? -s4[1] : s4[1];
        float s2 = dj ? -s4[2] : s4[2];
        float s3 = (di ^ dj) ? -s4[3] : s4[3];
        o4[di][dj] = a + 0.5f * (s4[0] + s1 + s2 + s3);
      }
    float* op = op0 + (size_t)(oy + 2 * i) * HP + ox + 2 * j;
    *(float2*)op        = make_float2(o4[0][0], o4[0][1]);
    *(float2*)(op + HP) = make_float2(o4[1][0], o4[1][1]);
    nacc += o4[0][0] * o4[0][0] + o4[0][1] * o4[0][1] +
            o4[1][0] * o4[1][0] + o4[1][1] * o4[1][1];
  }
  if (nrm != nullptr) {
#pragma unroll
    for (int m = 32; m; m >>= 1) nacc += __shfl_xor(nacc, m, 64);
    int lane = t & 63, wv_ = t >> 6;
    if (lane == 0) red[wv_] = nacc;
    __syncthreads();
    if (t == 0)
      atomicAdd(&nrm[b * C_ + c], red[0] + red[1] + red[2] + red[3]);
  }
}

// ---------------------------------------------------------------------------
// Bilinear 2x upsample 64->128, one block per (b,c) plane; norm direct-stored.
// ---------------------------------------------------------------------------
__global__ __launch_bounds__(256) void resize2x_norm(const float* __restrict__ in,
                                                     float* __restrict__ out,
                                                     float* __restrict__ rnq_sum) {
  const int bc = blockIdx.x;
  const int t = threadIdx.x;
  __shared__ float xs[64][65];
  __shared__ float red[4];
  const float* ip = in + (size_t)bc * Ns_;
  for (int p = t; p < 1024; p += 256) {
    float4 v = *(const float4*)&ip[p << 2];
    int r = p >> 4, c0 = (p & 15) << 2;
    xs[r][c0] = v.x; xs[r][c0 + 1] = v.y; xs[r][c0 + 2] = v.z; xs[r][c0 + 3] = v.w;
  }
  __syncthreads();
  float* op = out + (size_t)bc * Nb_;
  float nacc = 0.f;
#pragma unroll
  for (int it = 0; it < 16; ++it) {
    int p = t + it * 256;
    int i = p >> 5;
    int jc = p & 31;
    int ti = i >> 1; bool oi = i & 1;
    int r0 = oi ? ti : (ti > 0 ? ti - 1 : 0);
    int r1 = oi ? (ti < 63 ? ti + 1 : 63) : ti;
    float wr0 = oi ? 0.75f : 0.25f, wr1 = oi ? 0.25f : 0.75f;
    int cb = jc << 1;
    int cm1 = cb > 0 ? cb - 1 : 0;
    int cp2 = cb < 62 ? cb + 2 : 63;
    float a0 = xs[r0][cm1], a1 = xs[r0][cb], a2 = xs[r0][cb + 1], a3 = xs[r0][cp2];
    float b0 = xs[r1][cm1], b1 = xs[r1][cb], b2 = xs[r1][cb + 1], b3 = xs[r1][cp2];
    float ha0 = 0.25f * a0 + 0.75f * a1, hb0 = 0.25f * b0 + 0.75f * b1;
    float ha1 = 0.75f * a1 + 0.25f * a2, hb1 = 0.75f * b1 + 0.25f * b2;
    float ha2 = 0.25f * a1 + 0.75f * a2, hb2 = 0.25f * b1 + 0.75f * b2;
    float ha3 = 0.75f * a2 + 0.25f * a3, hb3 = 0.75f * b2 + 0.25f * b3;
    float4 o = make_float4(wr0 * ha0 + wr1 * hb0, wr0 * ha1 + wr1 * hb1,
                           wr0 * ha2 + wr1 * hb2, wr0 * ha3 + wr1 * hb3);
    *(float4*)&op[p << 2] = o;
    nacc += o.x * o.x + o.y * o.y + o.z * o.z + o.w * o.w;
  }
#pragma unroll
  for (int m = 32; m; m >>= 1) nacc += __shfl_xor(nacc, m, 64);
  int lane = t & 63, wv = t >> 6;
  if (lane == 0) red[wv] = nacc;
  __syncthreads();
  if (t == 0) rnq_sum[bc] = red[0] + red[1] + red[2] + red[3];
}

__global__ void zero_buf(float* __restrict__ p, int n) {
  int i = blockIdx.x * blockDim.x + threadIdx.x;
  if (i < n) p[i] = 0.f;
}

// ---------------------------------------------------------------------------
// Gram v2: 2x2 micro-tile per thread, k staged transposed (conflict-free
// float2 reads), q reads broadcast. grid (32 slices, 8, 2), 256 threads.
// ---------------------------------------------------------------------------
__global__ __launch_bounds__(256) void gram_qk(const float* __restrict__ q,
                                               const float* __restrict__ k,
                                               float* __restrict__ gram) {
  const int b = blockIdx.z, h = blockIdx.y, sl = blockIdx.x;
  constexpr int NS = Nb_ / 32;   // 512 n per slice
  const int n0 = sl * NS;
  const int t = threadIdx.x;
  const int tc = t >> 4, td = t & 15;       // c tile 2tc..2tc+1, d tile 2td..2td+1
  const float* qb = q + ((size_t)b * C_ + h * CHD_) * Nb_;
  const float* kb = k + ((size_t)b * C_ + h * CHD_) * Nb_;
  __shared__ float qs[32][132];             // [c][nn]
  __shared__ float kst[128][34];            // [nn][d] transposed
  float a00 = 0.f, a01 = 0.f, a10 = 0.f, a11 = 0.f;
  for (int nc = 0; nc < NS; nc += 128) {
    for (int i = t; i < 1024; i += 256) {
      int row = i >> 5, nc4 = (i & 31) << 2;
      float4 qv = *(const float4*)&qb[(size_t)row * Nb_ + n0 + nc + nc4];
      *(float4*)&qs[row][nc4] = qv;
      float4 kv = *(const float4*)&kb[(size_t)row * Nb_ + n0 + nc + nc4];
      kst[nc4 + 0][row] = kv.x; kst[nc4 + 1][row] = kv.y;
      kst[nc4 + 2][row] = kv.z; kst[nc4 + 3][row] = kv.w;
    }
    __syncthreads();
#pragma unroll 8
    for (int nn = 0; nn < 128; ++nn) {
      float q0 = qs[2 * tc][nn], q1 = qs[2 * tc + 1][nn];
      float2 kk = *(float2*)&kst[nn][2 * td];
      a00 = fmaf(q0, kk.x, a00); a01 = fmaf(q0, kk.y, a01);
      a10 = fmaf(q1, kk.x, a10); a11 = fmaf(q1, kk.y, a11);
    }
    __syncthreads();
  }
  float* gp = gram + ((size_t)(b * HEADS_ + h) * CHD_ + 2 * tc) * CHD_ + 2 * td;
  atomicAdd(&gp[0], a00);
  atomicAdd(&gp[1], a01);
  atomicAdd(&gp[CHD_], a10);
  atomicAdd(&gp[CHD_ + 1], a11);
}

// ---------------------------------------------------------------------------
// attn = softmax_d( gram * rsq(c) * rsk(d) * temp_h ), rs = 1/max(sqrt(sum),eps)
// ---------------------------------------------------------------------------
__global__ __launch_bounds__(1024) void attn_softmax(const float* __restrict__ gram,
                                                     const float* __restrict__ rnq_sum,
                                                     const float* __restrict__ rnk_sum,
                                                     const float* __restrict__ temp,
                                                     float* __restrict__ attn) {
  const int h = blockIdx.x, b = blockIdx.y;
  const int t = threadIdx.x;
  const int c = t >> 5, d = t & 31;
  size_t gi = ((size_t)(b * HEADS_ + h) * CHD_ + c) * CHD_ + d;
  float rq = 1.f / fmaxf(sqrtf(rnq_sum[b * C_ + h * CHD_ + c]), 1e-12f);
  float rk = 1.f / fmaxf(sqrtf(rnk_sum[b * C_ + h * CHD_ + d]), 1e-12f);
  float val = gram[gi] * rq * rk * temp[h];
  float m = val;
#pragma unroll
  for (int s = 16; s; s >>= 1) m = fmaxf(m, __shfl_xor(m, s, 64));
  float e = expf(val - m);
  float ssum = e;
#pragma unroll
  for (int s = 16; s; s >>= 1) ssum += __shfl_xor(ssum, s, 64);
  attn[gi] = e / ssum;
}

// ---------------------------------------------------------------------------
// Fused attn@v + proj-wtconv (1x1 kernels => per-2x2-block closed form).
// attn staged TRANSPOSED (at[d][c]); v loads as float2 pairs.
// ---------------------------------------------------------------------------
__global__ __launch_bounds__(256) void av_proj(const float* __restrict__ attn,
                                               const float* __restrict__ v,
                                               const float* __restrict__ p_bw,
                                               const float* __restrict__ p_bs,
                                               const float* __restrict__ p_ww,
                                               const float* __restrict__ p_ws,
                                               float* __restrict__ out) {
  const int bh = blockIdx.y;
  const int b = bh >> 3, h = bh & 7;
  const int half = threadIdx.x >> 7;
  const int pl = threadIdx.x & 127;
  const int p = blockIdx.x * 128 + pl;
  const int bi = p >> 6, bj = p & 63;
  __shared__ float at[32][36];
  for (int i = threadIdx.x; i < 1024; i += 256)
    at[i & 31][i >> 5] = attn[(size_t)bh * 1024 + i];
  __syncthreads();
  const float* vb = v + ((size_t)b * C_ + h * CHD_) * Nb_;
  const int n00 = (2 * bi) * Wb_ + 2 * bj;
  float acc[16][4] = {};
  for (int d = 0; d < 32; ++d) {
    const float* vp = vb + (size_t)d * Nb_ + n00;
    float2 vt = *(const float2*)vp;
    float2 vbt = *(const float2*)(vp + Wb_);
    float4 a0 = *(float4*)&at[d][half * 16];
    float4 a1 = *(float4*)&at[d][half * 16 + 4];
    float4 a2 = *(float4*)&at[d][half * 16 + 8];
    float4 a3 = *(float4*)&at[d][half * 16 + 12];
    float av[16] = {a0.x, a0.y, a0.z, a0.w, a1.x, a1.y, a1.z, a1.w,
                    a2.x, a2.y, a2.z, a2.w, a3.x, a3.y, a3.z, a3.w};
#pragma unroll
    for (int cc = 0; cc < 16; ++cc) {
      acc[cc][0] = fmaf(av[cc], vt.x,  acc[cc][0]);
      acc[cc][1] = fmaf(av[cc], vt.y,  acc[cc][1]);
      acc[cc][2] = fmaf(av[cc], vbt.x, acc[cc][2]);
      acc[cc][3] = fmaf(av[cc], vbt.y, acc[cc][3]);
    }
  }
  float* ob = out + ((size_t)b * C_ + h * CHD_) * Nb_;
#pragma unroll
  for (int cc = 0; cc < 16; ++cc) {
    int lc = half * 16 + cc;
    int gc = h * CHD_ + lc;
    float p00 = acc[cc][0], p01 = acc[cc][1], p10 = acc[cc][2], p11 = acc[cc][3];
    float ll = 0.5f * (p00 + p01 + p10 + p11) * (p_ww[gc * 4 + 0] * p_ws[gc * 4 + 0]);
    float hl = 0.5f * (p00 + p01 - p10 - p11) * (p_ww[gc * 4 + 1] * p_ws[gc * 4 + 1]);
    float lh = 0.5f * (p00 - p01 + p10 - p11) * (p_ww[gc * 4 + 2] * p_ws[gc * 4 + 2]);
    float hh = 0.5f * (p00 - p01 - p10 + p11) * (p_ww[gc * 4 + 3] * p_ws[gc * 4 + 3]);
    float bb = p_bw[gc] * p_bs[gc];
    float* op = ob + (size_t)lc * Nb_ + n00;
    *(float2*)op         = make_float2(p00 * bb + 0.5f * (ll + hl + lh + hh),
                                       p01 * bb + 0.5f * (ll + hl - lh - hh));
    *(float2*)(op + Wb_) = make_float2(p10 * bb + 0.5f * (ll - hl + lh - hh),
                                       p11 * bb + 0.5f * (ll - hl - lh + hh));
  }
}

// ---------------------------------------------------------------------------
extern "C" void kernel_launch(void* const* d_in, const int* in_sizes, int n_in,
                              void* d_out, int out_size, void* d_ws, size_t ws_size,
                              hipStream_t stream) {
  const float* x    = (const float*)d_in[0];
  const float* cf   = (const float*)d_in[1];
  const float* Wq   = (const float*)d_in[2];
  const float* Wk   = (const float*)d_in[3];
  const float* Wv   = (const float*)d_in[4];
  const float* temp = (const float*)d_in[5];
  const float* q_bw = (const float*)d_in[6];
  const float* q_bs = (const float*)d_in[7];
  const float* q_ww = (const float*)d_in[8];
  const float* q_ws = (const float*)d_in[9];
  const float* k_bw = (const float*)d_in[10];
  const float* k_bs = (const float*)d_in[11];
  const float* k_ww = (const float*)d_in[12];
  const float* k_ws = (const float*)d_in[13];
  const float* v_bw = (const float*)d_in[14];
  const float* v_bs = (const float*)d_in[15];
  const float* v_ww = (const float*)d_in[16];
  const float* v_ws = (const float*)d_in[17];
  const float* p_bw = (const float*)d_in[18];
  const float* p_bs = (const float*)d_in[19];
  const float* p_ww = (const float*)d_in[20];
  const float* p_ws = (const float*)d_in[21];

  // Workspace (floats); liveness reuse: Bb = k0 -> q_up.
  float* ws   = (float*)d_ws;
  float* A    = ws;                 // q0 [2,256,64,64]      2,097,152
  float* Bb   = A  + 2097152;       // k0 -> q_up            8,388,608
  float* Cb   = Bb + 8388608;       // v0                    8,388,608
  float* Fb   = Cb + 8388608;       // q1 [2,256,64,64]      2,097,152
  float* Gb   = Fb + 2097152;       // k1                    8,388,608
  float* Hb   = Gb + 8388608;       // v1                    8,388,608
  float* rnq  = Hb + 8388608;       // 512   (sumsq, direct write)
  float* rnk  = rnq + 512;          // 512   (sumsq, atomic)
  float* gram = rnk + 512;          // 16384 (atomic)
  float* attn = gram + 16384;       // 16384

  // 0) zero the atomic accumulators (rnk|gram contiguous = 16896 floats)
  zero_buf<<<(16896 + 255) / 256, 256, 0, stream>>>(rnk, 16896);

  // 1) q/k/v 1x1 channel-mix GEMMs (O-tile 32; big: 2 n/thread)
  gemm_1x1<Ns_><<<dim3(Ns_ / 256, C_ / 32, B_), 256, 0, stream>>>(x,  Wq, A);
  gemm_1x1<Nb_><<<dim3(Nb_ / 512, C_ / 32, B_), 256, 0, stream>>>(cf, Wk, Bb);
  gemm_1x1<Nb_><<<dim3(Nb_ / 512, C_ / 32, B_), 256, 0, stream>>>(cf, Wv, Cb);

  // 2) fused wtconv: q (64x64), k (128x128, +norm fold), v (128x128)
  wtconv_fused<64><<<dim3(1, C_, B_), 256, 0, stream>>>(A, q_bw, q_bs, q_ww, q_ws, Fb, nullptr);
  wtconv_fused<128><<<dim3(4, C_, B_), 256, 0, stream>>>(Bb, k_bw, k_bs, k_ww, k_ws, Gb, rnk);
  wtconv_fused<128><<<dim3(4, C_, B_), 256, 0, stream>>>(Cb, v_bw, v_bs, v_ww, v_ws, Hb, nullptr);

  // 3) upsample q1 -> q_up (into Bb; k0 dead) + rnq direct
  resize2x_norm<<<B_ * C_, 256, 0, stream>>>(Fb, Bb, rnq);

  // 4) gram + softmax
  gram_qk<<<dim3(32, HEADS_, B_), 256, 0, stream>>>(Bb, Gb, gram);
  attn_softmax<<<dim3(HEADS_, B_), 1024, 0, stream>>>(gram, rnq, rnk, temp, attn);

  // 5) fused attn@v + proj -> d_out
  av_proj<<<dim3(Nb_ / 4 / 128, B_ * HEADS_), 256, 0, stream>>>(
      attn, Hb, p_bw, p_bs, p_ww, p_ws, (float*)d_out);
}

// Round 8
// 340.872 us; speedup vs baseline: 1.1750x; 1.1750x over previous
//
#include <hip/hip_runtime.h>
#include <math.h>

// WaveletAtt: B=2, CIN=DIM=256, HEADS=8, wt_levels=1 Haar
constexpr int B_ = 2;
constexpr int C_ = 256;
constexpr int Hb_ = 128, Wb_ = 128;      // crossFeat / k / v / output spatial
constexpr int Nb_ = Hb_ * Wb_;           // 16384
constexpr int Hs_ = 64, Ws_ = 64;        // x / q spatial
constexpr int Ns_ = Hs_ * Ws_;           // 4096
constexpr int HEADS_ = 8;
constexpr int CHD_ = C_ / HEADS_;        // 32

typedef float f32x4 __attribute__((ext_vector_type(4)));

// ---------------------------------------------------------------------------
// GEMM v2 (round-5, known-good): 64(M)x128(N) tile, 256 threads, 4x8 micro,
// BK=32. Used for the small q GEMM.
// ---------------------------------------------------------------------------
template<int NTOT>
__global__ __launch_bounds__(256) void gemm_1x1(const float* __restrict__ in,
                                                const float* __restrict__ Wm,
                                                float* __restrict__ out) {
  constexpr int BK = 32;
  __shared__ float Wsh[BK][68];
  __shared__ float Xsh[BK][128];
  const int b  = blockIdx.z;
  const int o0 = blockIdx.y * 64;
  const int n0 = blockIdx.x * 128;
  const float* inb = in + (size_t)b * C_ * NTOT;
  const int t  = threadIdx.x;
  const int ty = t >> 4, tx = t & 15;
  float acc[4][8] = {};
  for (int k0 = 0; k0 < C_; k0 += BK) {
    { // stage W tile: conflict-free mapping (lane covers one o row, one kb octet)
      int oo = t & 63, kb = (t >> 6) << 3;
      const float* wp = Wm + (size_t)(o0 + oo) * C_ + k0 + kb;
      float4 w0 = *(const float4*)wp;
      float4 w1 = *(const float4*)(wp + 4);
      Wsh[kb + 0][oo] = w0.x; Wsh[kb + 1][oo] = w0.y;
      Wsh[kb + 2][oo] = w0.z; Wsh[kb + 3][oo] = w0.w;
      Wsh[kb + 4][oo] = w1.x; Wsh[kb + 5][oo] = w1.y;
      Wsh[kb + 6][oo] = w1.z; Wsh[kb + 7][oo] = w1.w;
    }
    { // stage X tile (wave-contiguous writes)
      int nn = (t & 31) << 2;
      int kr0 = t >> 5;
#pragma unroll
      for (int r = 0; r < 4; ++r) {
        int kr = kr0 + r * 8;
        *(float4*)&Xsh[kr][nn] = *(const float4*)(inb + (size_t)(k0 + kr) * NTOT + n0 + nn);
      }
    }
    __syncthreads();
#pragma unroll
    for (int kk = 0; kk < BK; ++kk) {
      float4 af = *(float4*)&Wsh[kk][ty * 4];
      float4 x0 = *(float4*)&Xsh[kk][tx * 4];
      float4 x1 = *(float4*)&Xsh[kk][tx * 4 + 64];
      float av[4] = {af.x, af.y, af.z, af.w};
      float xv[8] = {x0.x, x0.y, x0.z, x0.w, x1.x, x1.y, x1.z, x1.w};
#pragma unroll
      for (int i = 0; i < 4; ++i)
#pragma unroll
        for (int j = 0; j < 8; ++j)
          acc[i][j] = fmaf(av[i], xv[j], acc[i][j]);
    }
    __syncthreads();
  }
  float* ob = out + (size_t)b * C_ * NTOT;
#pragma unroll
  for (int i = 0; i < 4; ++i) {
    float* op = ob + (size_t)(o0 + ty * 4 + i) * NTOT + n0;
    *(float4*)(op + tx * 4)      = make_float4(acc[i][0], acc[i][1], acc[i][2], acc[i][3]);
    *(float4*)(op + tx * 4 + 64) = make_float4(acc[i][4], acc[i][5], acc[i][6], acc[i][7]);
  }
}

// ---------------------------------------------------------------------------
// Dual GEMM: k0 = Wk@cf and v0 = Wv@cf from ONE X staging (same tiling as v2).
// Per kk: 4 b128 LDS reads feed 64 FMA (2x arithmetic intensity of v2).
// ---------------------------------------------------------------------------
__global__ __launch_bounds__(256) void gemm_dual(const float* __restrict__ in,
                                                 const float* __restrict__ Wk,
                                                 const float* __restrict__ Wv,
                                                 float* __restrict__ outK,
                                                 float* __restrict__ outV) {
  constexpr int BK = 32;
  constexpr int NTOT = Nb_;
  __shared__ float WshK[BK][68];
  __shared__ float WshV[BK][68];
  __shared__ float Xsh[BK][128];
  const int b  = blockIdx.z;
  const int o0 = blockIdx.y * 64;
  const int n0 = blockIdx.x * 128;
  const float* inb = in + (size_t)b * C_ * NTOT;
  const int t  = threadIdx.x;
  const int ty = t >> 4, tx = t & 15;
  float accK[4][8] = {}, accV[4][8] = {};
  const int oo = t & 63, kb = (t >> 6) << 3;
  for (int k0 = 0; k0 < C_; k0 += BK) {
    {
      const float* wp = Wk + (size_t)(o0 + oo) * C_ + k0 + kb;
      float4 w0 = *(const float4*)wp;
      float4 w1 = *(const float4*)(wp + 4);
      WshK[kb + 0][oo] = w0.x; WshK[kb + 1][oo] = w0.y;
      WshK[kb + 2][oo] = w0.z; WshK[kb + 3][oo] = w0.w;
      WshK[kb + 4][oo] = w1.x; WshK[kb + 5][oo] = w1.y;
      WshK[kb + 6][oo] = w1.z; WshK[kb + 7][oo] = w1.w;
    }
    {
      const float* wp = Wv + (size_t)(o0 + oo) * C_ + k0 + kb;
      float4 w0 = *(const float4*)wp;
      float4 w1 = *(const float4*)(wp + 4);
      WshV[kb + 0][oo] = w0.x; WshV[kb + 1][oo] = w0.y;
      WshV[kb + 2][oo] = w0.z; WshV[kb + 3][oo] = w0.w;
      WshV[kb + 4][oo] = w1.x; WshV[kb + 5][oo] = w1.y;
      WshV[kb + 6][oo] = w1.z; WshV[kb + 7][oo] = w1.w;
    }
    {
      int nn = (t & 31) << 2;
      int kr0 = t >> 5;
#pragma unroll
      for (int r = 0; r < 4; ++r) {
        int kr = kr0 + r * 8;
        *(float4*)&Xsh[kr][nn] = *(const float4*)(inb + (size_t)(k0 + kr) * NTOT + n0 + nn);
      }
    }
    __syncthreads();
#pragma unroll
    for (int kk = 0; kk < BK; ++kk) {
      float4 ak = *(float4*)&WshK[kk][ty * 4];
      float4 avv = *(float4*)&WshV[kk][ty * 4];
      float4 x0 = *(float4*)&Xsh[kk][tx * 4];
      float4 x1 = *(float4*)&Xsh[kk][tx * 4 + 64];
      float akv[4] = {ak.x, ak.y, ak.z, ak.w};
      float avv4[4] = {avv.x, avv.y, avv.z, avv.w};
      float xv[8] = {x0.x, x0.y, x0.z, x0.w, x1.x, x1.y, x1.z, x1.w};
#pragma unroll
      for (int i = 0; i < 4; ++i)
#pragma unroll
        for (int j = 0; j < 8; ++j) {
          accK[i][j] = fmaf(akv[i], xv[j], accK[i][j]);
          accV[i][j] = fmaf(avv4[i], xv[j], accV[i][j]);
        }
    }
    __syncthreads();
  }
  float* obK = outK + (size_t)b * C_ * NTOT;
  float* obV = outV + (size_t)b * C_ * NTOT;
#pragma unroll
  for (int i = 0; i < 4; ++i) {
    size_t ro = (size_t)(o0 + ty * 4 + i) * NTOT + n0;
    *(float4*)(obK + ro + tx * 4)      = make_float4(accK[i][0], accK[i][1], accK[i][2], accK[i][3]);
    *(float4*)(obK + ro + tx * 4 + 64) = make_float4(accK[i][4], accK[i][5], accK[i][6], accK[i][7]);
    *(float4*)(obV + ro + tx * 4)      = make_float4(accV[i][0], accV[i][1], accV[i][2], accV[i][3]);
    *(float4*)(obV + ro + tx * 4 + 64) = make_float4(accV[i][4], accV[i][5], accV[i][6], accV[i][7]);
  }
}

// ---------------------------------------------------------------------------
// Fused WTConv (wt_levels=1 Haar). Subbands stored INTERLEAVED as f32x4
// (LL,HL,LH,HH) -> dw3x3 = 9 b128 reads + 36 vec-FMA per output-block.
// ---------------------------------------------------------------------------
template<int HP>   // plane is HP x HP (64 or 128)
__global__ __launch_bounds__(256) void wtconv_fused(
    const float* __restrict__ x, const float* __restrict__ bw,
    const float* __restrict__ bs, const float* __restrict__ ww,
    const float* __restrict__ wsc, float* __restrict__ out,
    float* __restrict__ nrm) {
  constexpr int NT = HP / 64;
  const int tile = blockIdx.x;
  const int c = blockIdx.y, b = blockIdx.z;
  const int oy = (tile / NT) * 64, ox = (tile % NT) * 64;
  const float* xp = x + ((size_t)(b * C_) + c) * HP * HP;

  __shared__ float xt[68][76];           // col m <-> gx = ox-4+m
  __shared__ f32x4 sb4[34][36];          // interleaved subbands (+1 halo)
  __shared__ float red[4];

  float wb[9];
#pragma unroll
  for (int i = 0; i < 9; ++i) wb[i] = bw[c * 9 + i];
  const float sbase = bs[c];
  f32x4 wv4[9]; f32x4 sv4;
#pragma unroll
  for (int i = 0; i < 9; ++i) {
    wv4[i].x = ww[(c * 4 + 0) * 9 + i];
    wv4[i].y = ww[(c * 4 + 1) * 9 + i];
    wv4[i].z = ww[(c * 4 + 2) * 9 + i];
    wv4[i].w = ww[(c * 4 + 3) * 9 + i];
  }
  sv4.x = wsc[c * 4 + 0]; sv4.y = wsc[c * 4 + 1];
  sv4.z = wsc[c * 4 + 2]; sv4.w = wsc[c * 4 + 3];

  const int t = threadIdx.x;
  // stage 68 rows x 18 float4 (cols [ox-4, ox+68)); zero outside plane
  for (int p = t; p < 68 * 18; p += 256) {
    int r = p / 18, k4 = (p % 18) << 2;
    int gy = oy - 2 + r, gx = ox - 4 + k4;
    float4 v = make_float4(0.f, 0.f, 0.f, 0.f);
    if ((unsigned)gy < (unsigned)HP && (unsigned)gx < (unsigned)HP)
      v = *(const float4*)(xp + (size_t)gy * HP + gx);
    *(float4*)&xt[r][k4] = v;
  }
  __syncthreads();
  // Haar analysis at 34x34 positions (xt col offset +2)
  for (int p = t; p < 34 * 34; p += 256) {
    int i = p / 34, j = p % 34;
    float p00 = xt[2 * i][2 * j + 2],     p01 = xt[2 * i][2 * j + 3];
    float p10 = xt[2 * i + 1][2 * j + 2], p11 = xt[2 * i + 1][2 * j + 3];
    f32x4 s;
    s.x = 0.5f * (p00 + p01 + p10 + p11);
    s.y = 0.5f * (p00 + p01 - p10 - p11);
    s.z = 0.5f * (p00 - p01 + p10 - p11);
    s.w = 0.5f * (p00 - p01 - p10 + p11);
    sb4[i][j] = s;
  }
  __syncthreads();

  float nacc = 0.f;
  float* op0 = out + ((size_t)(b * C_) + c) * HP * HP;
  for (int p = t; p < 32 * 32; p += 256) {
    int i = p >> 5, j = p & 31;
    f32x4 a4 = {0.f, 0.f, 0.f, 0.f};
#pragma unroll
    for (int dh = 0; dh < 3; ++dh)
#pragma unroll
      for (int dw = 0; dw < 3; ++dw)
        a4 += sb4[i + dh][j + dw] * wv4[dh * 3 + dw];
    f32x4 s4 = a4 * sv4;
    float pp[4][4];
#pragma unroll
    for (int r = 0; r < 4; ++r)
#pragma unroll
      for (int cc = 0; cc < 4; ++cc)
        pp[r][cc] = xt[2 * i + 1 + r][2 * j + 3 + cc];
    float o4[2][2];
#pragma unroll
    for (int di = 0; di < 2; ++di)
#pragma unroll
      for (int dj = 0; dj < 2; ++dj) {
        float a = 0.f;
#pragma unroll
        for (int dh = 0; dh < 3; ++dh)
#pragma unroll
          for (int dw = 0; dw < 3; ++dw)
            a = fmaf(pp[di + dh][dj + dw], wb[dh * 3 + dw], a);
        a *= sbase;
        float s1 = di ? -s4.y : s4.y;
        float s2 = dj ? -s4.z : s4.z;
        float s3 = (di ^ dj) ? -s4.w : s4.w;
        o4[di][dj] = a + 0.5f * (s4.x + s1 + s2 + s3);
      }
    float* op = op0 + (size_t)(oy + 2 * i) * HP + ox + 2 * j;
    *(float2*)op        = make_float2(o4[0][0], o4[0][1]);
    *(float2*)(op + HP) = make_float2(o4[1][0], o4[1][1]);
    nacc += o4[0][0] * o4[0][0] + o4[0][1] * o4[0][1] +
            o4[1][0] * o4[1][0] + o4[1][1] * o4[1][1];
  }
  if (nrm != nullptr) {
#pragma unroll
    for (int m = 32; m; m >>= 1) nacc += __shfl_xor(nacc, m, 64);
    int lane = t & 63, wv_ = t >> 6;
    if (lane == 0) red[wv_] = nacc;
    __syncthreads();
    if (t == 0)
      atomicAdd(&nrm[b * C_ + c], red[0] + red[1] + red[2] + red[3]);
  }
}

// ---------------------------------------------------------------------------
// Bilinear 2x upsample 64->128, one block per (b,c) plane; norm direct-stored.
// ---------------------------------------------------------------------------
__global__ __launch_bounds__(256) void resize2x_norm(const float* __restrict__ in,
                                                     float* __restrict__ out,
                                                     float* __restrict__ rnq_sum) {
  const int bc = blockIdx.x;
  const int t = threadIdx.x;
  __shared__ float xs[64][65];
  __shared__ float red[4];
  const float* ip = in + (size_t)bc * Ns_;
  for (int p = t; p < 1024; p += 256) {
    float4 v = *(const float4*)&ip[p << 2];
    int r = p >> 4, c0 = (p & 15) << 2;
    xs[r][c0] = v.x; xs[r][c0 + 1] = v.y; xs[r][c0 + 2] = v.z; xs[r][c0 + 3] = v.w;
  }
  __syncthreads();
  float* op = out + (size_t)bc * Nb_;
  float nacc = 0.f;
#pragma unroll
  for (int it = 0; it < 16; ++it) {
    int p = t + it * 256;
    int i = p >> 5;
    int jc = p & 31;
    int ti = i >> 1; bool oi = i & 1;
    int r0 = oi ? ti : (ti > 0 ? ti - 1 : 0);
    int r1 = oi ? (ti < 63 ? ti + 1 : 63) : ti;
    float wr0 = oi ? 0.75f : 0.25f, wr1 = oi ? 0.25f : 0.75f;
    int cb = jc << 1;
    int cm1 = cb > 0 ? cb - 1 : 0;
    int cp2 = cb < 62 ? cb + 2 : 63;
    float a0 = xs[r0][cm1], a1 = xs[r0][cb], a2 = xs[r0][cb + 1], a3 = xs[r0][cp2];
    float b0 = xs[r1][cm1], b1 = xs[r1][cb], b2 = xs[r1][cb + 1], b3 = xs[r1][cp2];
    float ha0 = 0.25f * a0 + 0.75f * a1, hb0 = 0.25f * b0 + 0.75f * b1;
    float ha1 = 0.75f * a1 + 0.25f * a2, hb1 = 0.75f * b1 + 0.25f * b2;
    float ha2 = 0.25f * a1 + 0.75f * a2, hb2 = 0.25f * b1 + 0.75f * b2;
    float ha3 = 0.75f * a2 + 0.25f * a3, hb3 = 0.75f * b2 + 0.25f * b3;
    float4 o = make_float4(wr0 * ha0 + wr1 * hb0, wr0 * ha1 + wr1 * hb1,
                           wr0 * ha2 + wr1 * hb2, wr0 * ha3 + wr1 * hb3);
    *(float4*)&op[p << 2] = o;
    nacc += o.x * o.x + o.y * o.y + o.z * o.z + o.w * o.w;
  }
#pragma unroll
  for (int m = 32; m; m >>= 1) nacc += __shfl_xor(nacc, m, 64);
  int lane = t & 63, wv = t >> 6;
  if (lane == 0) red[wv] = nacc;
  __syncthreads();
  if (t == 0) rnq_sum[bc] = red[0] + red[1] + red[2] + red[3];
}

__global__ void zero_buf(float* __restrict__ p, int n) {
  int i = blockIdx.x * blockDim.x + threadIdx.x;
  if (i < n) p[i] = 0.f;
}

// ---------------------------------------------------------------------------
// Gram: 2x2 micro-tile per thread, k staged transposed. grid (32,8,2), 256 thr.
// ---------------------------------------------------------------------------
__global__ __launch_bounds__(256) void gram_qk(const float* __restrict__ q,
                                               const float* __restrict__ k,
                                               float* __restrict__ gram) {
  const int b = blockIdx.z, h = blockIdx.y, sl = blockIdx.x;
  constexpr int NS = Nb_ / 32;   // 512 n per slice
  const int n0 = sl * NS;
  const int t = threadIdx.x;
  const int tc = t >> 4, td = t & 15;
  const float* qb = q + ((size_t)b * C_ + h * CHD_) * Nb_;
  const float* kb = k + ((size_t)b * C_ + h * CHD_) * Nb_;
  __shared__ float qs[32][132];
  __shared__ float kst[128][34];
  float a00 = 0.f, a01 = 0.f, a10 = 0.f, a11 = 0.f;
  for (int nc = 0; nc < NS; nc += 128) {
    for (int i = t; i < 1024; i += 256) {
      int row = i >> 5, nc4 = (i & 31) << 2;
      float4 qv = *(const float4*)&qb[(size_t)row * Nb_ + n0 + nc + nc4];
      *(float4*)&qs[row][nc4] = qv;
      float4 kv = *(const float4*)&kb[(size_t)row * Nb_ + n0 + nc + nc4];
      kst[nc4 + 0][row] = kv.x; kst[nc4 + 1][row] = kv.y;
      kst[nc4 + 2][row] = kv.z; kst[nc4 + 3][row] = kv.w;
    }
    __syncthreads();
#pragma unroll 8
    for (int nn = 0; nn < 128; ++nn) {
      float q0 = qs[2 * tc][nn], q1 = qs[2 * tc + 1][nn];
      float2 kk = *(float2*)&kst[nn][2 * td];
      a00 = fmaf(q0, kk.x, a00); a01 = fmaf(q0, kk.y, a01);
      a10 = fmaf(q1, kk.x, a10); a11 = fmaf(q1, kk.y, a11);
    }
    __syncthreads();
  }
  float* gp = gram + ((size_t)(b * HEADS_ + h) * CHD_ + 2 * tc) * CHD_ + 2 * td;
  atomicAdd(&gp[0], a00);
  atomicAdd(&gp[1], a01);
  atomicAdd(&gp[CHD_], a10);
  atomicAdd(&gp[CHD_ + 1], a11);
}

// ---------------------------------------------------------------------------
// attn = softmax_d( gram * rsq(c) * rsk(d) * temp_h )
// ---------------------------------------------------------------------------
__global__ __launch_bounds__(1024) void attn_softmax(const float* __restrict__ gram,
                                                     const float* __restrict__ rnq_sum,
                                                     const float* __restrict__ rnk_sum,
                                                     const float* __restrict__ temp,
                                                     float* __restrict__ attn) {
  const int h = blockIdx.x, b = blockIdx.y;
  const int t = threadIdx.x;
  const int c = t >> 5, d = t & 31;
  size_t gi = ((size_t)(b * HEADS_ + h) * CHD_ + c) * CHD_ + d;
  float rq = 1.f / fmaxf(sqrtf(rnq_sum[b * C_ + h * CHD_ + c]), 1e-12f);
  float rk = 1.f / fmaxf(sqrtf(rnk_sum[b * C_ + h * CHD_ + d]), 1e-12f);
  float val = gram[gi] * rq * rk * temp[h];
  float m = val;
#pragma unroll
  for (int s = 16; s; s >>= 1) m = fmaxf(m, __shfl_xor(m, s, 64));
  float e = expf(val - m);
  float ssum = e;
#pragma unroll
  for (int s = 16; s; s >>= 1) ssum += __shfl_xor(ssum, s, 64);
  attn[gi] = e / ssum;
}

// ---------------------------------------------------------------------------
// Fused attn@v + proj-wtconv (1x1 => per-2x2-block closed form).
// ---------------------------------------------------------------------------
__global__ __launch_bounds__(256) void av_proj(const float* __restrict__ attn,
                                               const float* __restrict__ v,
                                               const float* __restrict__ p_bw,
                                               const float* __restrict__ p_bs,
                                               const float* __restrict__ p_ww,
                                               const float* __restrict__ p_ws,
                                               float* __restrict__ out) {
  const int bh = blockIdx.y;
  const int b = bh >> 3, h = bh & 7;
  const int half = threadIdx.x >> 7;
  const int pl = threadIdx.x & 127;
  const int p = blockIdx.x * 128 + pl;
  const int bi = p >> 6, bj = p & 63;
  __shared__ float at[32][36];
  for (int i = threadIdx.x; i < 1024; i += 256)
    at[i & 31][i >> 5] = attn[(size_t)bh * 1024 + i];
  __syncthreads();
  const float* vb = v + ((size_t)b * C_ + h * CHD_) * Nb_;
  const int n00 = (2 * bi) * Wb_ + 2 * bj;
  float acc[16][4] = {};
  for (int d = 0; d < 32; ++d) {
    const float* vp = vb + (size_t)d * Nb_ + n00;
    float2 vt = *(const float2*)vp;
    float2 vbt = *(const float2*)(vp + Wb_);
    float4 a0 = *(float4*)&at[d][half * 16];
    float4 a1 = *(float4*)&at[d][half * 16 + 4];
    float4 a2 = *(float4*)&at[d][half * 16 + 8];
    float4 a3 = *(float4*)&at[d][half * 16 + 12];
    float av[16] = {a0.x, a0.y, a0.z, a0.w, a1.x, a1.y, a1.z, a1.w,
                    a2.x, a2.y, a2.z, a2.w, a3.x, a3.y, a3.z, a3.w};
#pragma unroll
    for (int cc = 0; cc < 16; ++cc) {
      acc[cc][0] = fmaf(av[cc], vt.x,  acc[cc][0]);
      acc[cc][1] = fmaf(av[cc], vt.y,  acc[cc][1]);
      acc[cc][2] = fmaf(av[cc], vbt.x, acc[cc][2]);
      acc[cc][3] = fmaf(av[cc], vbt.y, acc[cc][3]);
    }
  }
  float* ob = out + ((size_t)b * C_ + h * CHD_) * Nb_;
#pragma unroll
  for (int cc = 0; cc < 16; ++cc) {
    int lc = half * 16 + cc;
    int gc = h * CHD_ + lc;
    float p00 = acc[cc][0], p01 = acc[cc][1], p10 = acc[cc][2], p11 = acc[cc][3];
    float ll = 0.5f * (p00 + p01 + p10 + p11) * (p_ww[gc * 4 + 0] * p_ws[gc * 4 + 0]);
    float hl = 0.5f * (p00 + p01 - p10 - p11) * (p_ww[gc * 4 + 1] * p_ws[gc * 4 + 1]);
    float lh = 0.5f * (p00 - p01 + p10 - p11) * (p_ww[gc * 4 + 2] * p_ws[gc * 4 + 2]);
    float hh = 0.5f * (p00 - p01 - p10 + p11) * (p_ww[gc * 4 + 3] * p_ws[gc * 4 + 3]);
    float bb = p_bw[gc] * p_bs[gc];
    float* op = ob + (size_t)lc * Nb_ + n00;
    *(float2*)op         = make_float2(p00 * bb + 0.5f * (ll + hl + lh + hh),
                                       p01 * bb + 0.5f * (ll + hl - lh - hh));
    *(float2*)(op + Wb_) = make_float2(p10 * bb + 0.5f * (ll - hl + lh - hh),
                                       p11 * bb + 0.5f * (ll - hl - lh + hh));
  }
}

// ---------------------------------------------------------------------------
extern "C" void kernel_launch(void* const* d_in, const int* in_sizes, int n_in,
                              void* d_out, int out_size, void* d_ws, size_t ws_size,
                              hipStream_t stream) {
  const float* x    = (const float*)d_in[0];
  const float* cf   = (const float*)d_in[1];
  const float* Wq   = (const float*)d_in[2];
  const float* Wk   = (const float*)d_in[3];
  const float* Wv   = (const float*)d_in[4];
  const float* temp = (const float*)d_in[5];
  const float* q_bw = (const float*)d_in[6];
  const float* q_bs = (const float*)d_in[7];
  const float* q_ww = (const float*)d_in[8];
  const float* q_ws = (const float*)d_in[9];
  const float* k_bw = (const float*)d_in[10];
  const float* k_bs = (const float*)d_in[11];
  const float* k_ww = (const float*)d_in[12];
  const float* k_ws = (const float*)d_in[13];
  const float* v_bw = (const float*)d_in[14];
  const float* v_bs = (const float*)d_in[15];
  const float* v_ww = (const float*)d_in[16];
  const float* v_ws = (const float*)d_in[17];
  const float* p_bw = (const float*)d_in[18];
  const float* p_bs = (const float*)d_in[19];
  const float* p_ww = (const float*)d_in[20];
  const float* p_ws = (const float*)d_in[21];

  // Workspace (floats); liveness reuse: Bb = k0 -> q_up.
  float* ws   = (float*)d_ws;
  float* A    = ws;                 // q0 [2,256,64,64]      2,097,152
  float* Bb   = A  + 2097152;       // k0 -> q_up            8,388,608
  float* Cb   = Bb + 8388608;       // v0                    8,388,608
  float* Fb   = Cb + 8388608;       // q1 [2,256,64,64]      2,097,152
  float* Gb   = Fb + 2097152;       // k1                    8,388,608
  float* Hb   = Gb + 8388608;       // v1                    8,388,608
  float* rnq  = Hb + 8388608;       // 512   (sumsq, direct write)
  float* rnk  = rnq + 512;          // 512   (sumsq, atomic)
  float* gram = rnk + 512;          // 16384 (atomic)
  float* attn = gram + 16384;       // 16384

  // 0) zero the atomic accumulators (rnk|gram contiguous = 16896 floats)
  zero_buf<<<(16896 + 255) / 256, 256, 0, stream>>>(rnk, 16896);

  // 1) q GEMM (v2) + fused k/v dual GEMM
  gemm_1x1<Ns_><<<dim3(Ns_ / 128, C_ / 64, B_), 256, 0, stream>>>(x, Wq, A);
  gemm_dual<<<dim3(Nb_ / 128, C_ / 64, B_), 256, 0, stream>>>(cf, Wk, Wv, Bb, Cb);

  // 2) fused wtconv: q (64x64), k (128x128, +norm fold), v (128x128)
  wtconv_fused<64><<<dim3(1, C_, B_), 256, 0, stream>>>(A, q_bw, q_bs, q_ww, q_ws, Fb, nullptr);
  wtconv_fused<128><<<dim3(4, C_, B_), 256, 0, stream>>>(Bb, k_bw, k_bs, k_ww, k_ws, Gb, rnk);
  wtconv_fused<128><<<dim3(4, C_, B_), 256, 0, stream>>>(Cb, v_bw, v_bs, v_ww, v_ws, Hb, nullptr);

  // 3) upsample q1 -> q_up (into Bb; k0 dead) + rnq direct
  resize2x_norm<<<B_ * C_, 256, 0, stream>>>(Fb, Bb, rnq);

  // 4) gram + softmax
  gram_qk<<<dim3(32, HEADS_, B_), 256, 0, stream>>>(Bb, Gb, gram);
  attn_softmax<<<dim3(HEADS_, B_), 1024, 0, stream>>>(gram, rnq, rnk, temp, attn);

  // 5) fused attn@v + proj -> d_out
  av_proj<<<dim3(Nb_ / 4 / 128, B_ * HEADS_), 256, 0, stream>>>(
      attn, Hb, p_bw, p_bs, p_ww, p_ws, (float*)d_out);
}

// Round 9
// 286.634 us; speedup vs baseline: 1.3974x; 1.1892x over previous
//
#include <hip/hip_runtime.h>
#include <math.h>

// WaveletAtt: B=2, CIN=DIM=256, HEADS=8, wt_levels=1 Haar
constexpr int B_ = 2;
constexpr int C_ = 256;
constexpr int Hb_ = 128, Wb_ = 128;      // crossFeat / k / v / output spatial
constexpr int Nb_ = Hb_ * Wb_;           // 16384
constexpr int Hs_ = 64, Ws_ = 64;        // x / q spatial
constexpr int Ns_ = Hs_ * Ws_;           // 4096
constexpr int HEADS_ = 8;
constexpr int CHD_ = C_ / HEADS_;        // 32

typedef float f32x4 __attribute__((ext_vector_type(4)));
typedef short bf16x8 __attribute__((ext_vector_type(8)));          // 8 bf16 = 4 VGPR
typedef unsigned short u16x8 __attribute__((ext_vector_type(8)));  // 16B vector

// f32 -> bf16(hi) + bf16(lo), RNE both. x ≈ hi + lo, residual ~2^-18 rel.
__device__ inline void cvt_split(float f, unsigned short& h, unsigned short& l) {
  unsigned u = __float_as_uint(f);
  unsigned r = u + 0x7fffu + ((u >> 16) & 1u);
  h = (unsigned short)(r >> 16);
  float hf = __uint_as_float((unsigned)h << 16);
  float lo = f - hf;
  unsigned u2 = __float_as_uint(lo);
  unsigned r2 = u2 + 0x7fffu + ((u2 >> 16) & 1u);
  l = (unsigned short)(r2 >> 16);
}

// ---------------------------------------------------------------------------
// Split+transpose: X f32 [b][C][NTOT] -> Xh,Xl bf16-bits [b][NTOT][C]
// 64x64 tiles via LDS. Coalesced read (float4) and write (ushort8, 64B/4lanes).
// ---------------------------------------------------------------------------
__global__ __launch_bounds__(256) void cvt_split_T(const float* __restrict__ X,
                                                   unsigned short* __restrict__ Xh,
                                                   unsigned short* __restrict__ Xl,
                                                   int NTOT) {
  __shared__ float xs[64][72];   // 72: float4-aligned rows
  const int b  = blockIdx.z;
  const int c0 = blockIdx.y * 64;
  const int n0 = blockIdx.x * 64;
  const int t  = threadIdx.x;
  const float* xb = X + ((size_t)(b * C_ + c0)) * NTOT + n0;
  {
    int cl = t >> 4, n4 = (t & 15) << 2;
#pragma unroll
    for (int i = 0; i < 4; ++i) {
      float4 v = *(const float4*)(xb + (size_t)(cl + 16 * i) * NTOT + n4);
      *(float4*)&xs[cl + 16 * i][n4] = v;
    }
  }
  __syncthreads();
  const int n_l = t >> 2, cqb = t & 3;
  size_t obase = ((size_t)b * NTOT + n0 + n_l) * C_ + c0;
#pragma unroll
  for (int it = 0; it < 2; ++it) {
    int cq = it * 4 + cqb;       // 0..7 -> c offset cq*8
    u16x8 hv, lv;
#pragma unroll
    for (int j = 0; j < 8; ++j) {
      unsigned short h, l;
      cvt_split(xs[cq * 8 + j][n_l], h, l);
      hv[j] = h; lv[j] = l;
    }
    *(u16x8*)(Xh + obase + cq * 8) = hv;
    *(u16x8*)(Xl + obase + cq * 8) = lv;
  }
}

// Split Wq|Wk|Wv [o][c] f32 -> packed hi/lo bf16 planes (no transpose).
// Wp layout: m in {0,1,2}: hi at m*131072, lo at m*131072+65536 (ushort idx).
__global__ void cvt_w(const float* __restrict__ Wq, const float* __restrict__ Wk,
                      const float* __restrict__ Wv, unsigned short* __restrict__ Wp) {
  int i = blockIdx.x * 256 + threadIdx.x;   // 0 .. 3*65536-1
  int m = i >> 16, idx = i & 65535;
  const float* src = (m == 0) ? Wq : (m == 1) ? Wk : Wv;
  unsigned short h, l;
  cvt_split(src[idx], h, l);
  Wp[(size_t)m * 131072 + idx] = h;
  Wp[(size_t)m * 131072 + 65536 + idx] = l;
}

// ---------------------------------------------------------------------------
// MFMA GEMM: out[b][o][n] = sum_c W[o][c]*X[c][n] via split-bf16
// (Wh@Xh + Wh@Xl + Wl@Xh). Block 64(o)x64(n), 4 waves, wave = 16 o-rows.
// A-frags from global W planes (L2-resident); B staged in LDS [n][k] pad-40.
// mfma_f32_16x16x32_bf16: A lane: row=l&15,k=(l>>4)*8+j; B lane: col=l&15,
// k=(l>>4)*8+j; D lane reg r: row=(l>>4)*4+r, col=l&15 (m89-verified).
// ---------------------------------------------------------------------------
template<bool DUAL>
__global__ __launch_bounds__(256) void gemm_mfma(
    const unsigned short* __restrict__ XhT, const unsigned short* __restrict__ XlT,
    const unsigned short* __restrict__ Wh1, const unsigned short* __restrict__ Wl1,
    const unsigned short* __restrict__ Wh2, const unsigned short* __restrict__ Wl2,
    float* __restrict__ out1, float* __restrict__ out2, int NTOT) {
  __shared__ __align__(16) unsigned short XhL[64][40];   // pad 40: 80B rows, b128 ok
  __shared__ __align__(16) unsigned short XlL[64][40];
  const int b  = blockIdx.z;
  const int o0 = blockIdx.y * 64;
  const int n0 = blockIdx.x * 64;
  const int t  = threadIdx.x;
  const int w = t >> 6, lane = t & 63;
  const int lr = lane & 15, lk = lane >> 4;
  const unsigned short* xh = XhT + ((size_t)b * NTOT + n0) * C_;
  const unsigned short* xl = XlT + ((size_t)b * NTOT + n0) * C_;
  const int arow = o0 + w * 16 + lr;
  f32x4 acc1[4] = {};
  f32x4 acc2[4] = {};
  const int sn = t >> 2, scq = (t & 3) << 3;   // staging: n row, k octet
  for (int c0 = 0; c0 < C_; c0 += 32) {
    { // stage X tile [64 n][32 k] hi+lo (one ushort8 each per thread)
      size_t off = (size_t)sn * C_ + c0 + scq;
      *(u16x8*)&XhL[sn][scq] = *(const u16x8*)(xh + off);
      *(u16x8*)&XlL[sn][scq] = *(const u16x8*)(xl + off);
    }
    // A fragments (8 consecutive c of one o-row)
    size_t aoff = (size_t)arow * C_ + c0 + lk * 8;
    bf16x8 a1h = *(const bf16x8*)(Wh1 + aoff);
    bf16x8 a1l = *(const bf16x8*)(Wl1 + aoff);
    bf16x8 a2h, a2l;
    if constexpr (DUAL) {
      a2h = *(const bf16x8*)(Wh2 + aoff);
      a2l = *(const bf16x8*)(Wl2 + aoff);
    }
    __syncthreads();
#pragma unroll
    for (int s = 0; s < 4; ++s) {
      bf16x8 bh = *(const bf16x8*)&XhL[s * 16 + lr][lk * 8];
      bf16x8 bl = *(const bf16x8*)&XlL[s * 16 + lr][lk * 8];
      acc1[s] = __builtin_amdgcn_mfma_f32_16x16x32_bf16(a1h, bh, acc1[s], 0, 0, 0);
      acc1[s] = __builtin_amdgcn_mfma_f32_16x16x32_bf16(a1h, bl, acc1[s], 0, 0, 0);
      acc1[s] = __builtin_amdgcn_mfma_f32_16x16x32_bf16(a1l, bh, acc1[s], 0, 0, 0);
      if constexpr (DUAL) {
        acc2[s] = __builtin_amdgcn_mfma_f32_16x16x32_bf16(a2h, bh, acc2[s], 0, 0, 0);
        acc2[s] = __builtin_amdgcn_mfma_f32_16x16x32_bf16(a2h, bl, acc2[s], 0, 0, 0);
        acc2[s] = __builtin_amdgcn_mfma_f32_16x16x32_bf16(a2l, bh, acc2[s], 0, 0, 0);
      }
    }
    __syncthreads();
  }
  // epilogue: D row = lk*4+r, col = lr
  float* o1 = out1 + ((size_t)(b * C_ + o0 + w * 16)) * NTOT + n0;
#pragma unroll
  for (int s = 0; s < 4; ++s)
#pragma unroll
    for (int r = 0; r < 4; ++r)
      o1[(size_t)(lk * 4 + r) * NTOT + s * 16 + lr] = acc1[s][r];
  if constexpr (DUAL) {
    float* o2 = out2 + ((size_t)(b * C_ + o0 + w * 16)) * NTOT + n0;
#pragma unroll
    for (int s = 0; s < 4; ++s)
#pragma unroll
      for (int r = 0; r < 4; ++r)
        o2[(size_t)(lk * 4 + r) * NTOT + s * 16 + lr] = acc2[s][r];
  }
}

// ---------------------------------------------------------------------------
// Fused WTConv (wt_levels=1 Haar). Subbands interleaved f32x4 (unchanged).
// ---------------------------------------------------------------------------
template<int HP>
__global__ __launch_bounds__(256) void wtconv_fused(
    const float* __restrict__ x, const float* __restrict__ bw,
    const float* __restrict__ bs, const float* __restrict__ ww,
    const float* __restrict__ wsc, float* __restrict__ out,
    float* __restrict__ nrm) {
  constexpr int NT = HP / 64;
  const int tile = blockIdx.x;
  const int c = blockIdx.y, b = blockIdx.z;
  const int oy = (tile / NT) * 64, ox = (tile % NT) * 64;
  const float* xp = x + ((size_t)(b * C_) + c) * HP * HP;

  __shared__ float xt[68][76];
  __shared__ f32x4 sb4[34][36];
  __shared__ float red[4];

  float wb[9];
#pragma unroll
  for (int i = 0; i < 9; ++i) wb[i] = bw[c * 9 + i];
  const float sbase = bs[c];
  f32x4 wv4[9]; f32x4 sv4;
#pragma unroll
  for (int i = 0; i < 9; ++i) {
    wv4[i].x = ww[(c * 4 + 0) * 9 + i];
    wv4[i].y = ww[(c * 4 + 1) * 9 + i];
    wv4[i].z = ww[(c * 4 + 2) * 9 + i];
    wv4[i].w = ww[(c * 4 + 3) * 9 + i];
  }
  sv4.x = wsc[c * 4 + 0]; sv4.y = wsc[c * 4 + 1];
  sv4.z = wsc[c * 4 + 2]; sv4.w = wsc[c * 4 + 3];

  const int t = threadIdx.x;
  for (int p = t; p < 68 * 18; p += 256) {
    int r = p / 18, k4 = (p % 18) << 2;
    int gy = oy - 2 + r, gx = ox - 4 + k4;
    float4 v = make_float4(0.f, 0.f, 0.f, 0.f);
    if ((unsigned)gy < (unsigned)HP && (unsigned)gx < (unsigned)HP)
      v = *(const float4*)(xp + (size_t)gy * HP + gx);
    *(float4*)&xt[r][k4] = v;
  }
  __syncthreads();
  for (int p = t; p < 34 * 34; p += 256) {
    int i = p / 34, j = p % 34;
    float p00 = xt[2 * i][2 * j + 2],     p01 = xt[2 * i][2 * j + 3];
    float p10 = xt[2 * i + 1][2 * j + 2], p11 = xt[2 * i + 1][2 * j + 3];
    f32x4 s;
    s.x = 0.5f * (p00 + p01 + p10 + p11);
    s.y = 0.5f * (p00 + p01 - p10 - p11);
    s.z = 0.5f * (p00 - p01 + p10 - p11);
    s.w = 0.5f * (p00 - p01 - p10 + p11);
    sb4[i][j] = s;
  }
  __syncthreads();

  float nacc = 0.f;
  float* op0 = out + ((size_t)(b * C_) + c) * HP * HP;
  for (int p = t; p < 32 * 32; p += 256) {
    int i = p >> 5, j = p & 31;
    f32x4 a4 = {0.f, 0.f, 0.f, 0.f};
#pragma unroll
    for (int dh = 0; dh < 3; ++dh)
#pragma unroll
      for (int dw = 0; dw < 3; ++dw)
        a4 += sb4[i + dh][j + dw] * wv4[dh * 3 + dw];
    f32x4 s4 = a4 * sv4;
    float pp[4][4];
#pragma unroll
    for (int r = 0; r < 4; ++r)
#pragma unroll
      for (int cc = 0; cc < 4; ++cc)
        pp[r][cc] = xt[2 * i + 1 + r][2 * j + 3 + cc];
    float o4[2][2];
#pragma unroll
    for (int di = 0; di < 2; ++di)
#pragma unroll
      for (int dj = 0; dj < 2; ++dj) {
        float a = 0.f;
#pragma unroll
        for (int dh = 0; dh < 3; ++dh)
#pragma unroll
          for (int dw = 0; dw < 3; ++dw)
            a = fmaf(pp[di + dh][dj + dw], wb[dh * 3 + dw], a);
        a *= sbase;
        float s1 = di ? -s4.y : s4.y;
        float s2 = dj ? -s4.z : s4.z;
        float s3 = (di ^ dj) ? -s4.w : s4.w;
        o4[di][dj] = a + 0.5f * (s4.x + s1 + s2 + s3);
      }
    float* op = op0 + (size_t)(oy + 2 * i) * HP + ox + 2 * j;
    *(float2*)op        = make_float2(o4[0][0], o4[0][1]);
    *(float2*)(op + HP) = make_float2(o4[1][0], o4[1][1]);
    nacc += o4[0][0] * o4[0][0] + o4[0][1] * o4[0][1] +
            o4[1][0] * o4[1][0] + o4[1][1] * o4[1][1];
  }
  if (nrm != nullptr) {
#pragma unroll
    for (int m = 32; m; m >>= 1) nacc += __shfl_xor(nacc, m, 64);
    int lane = t & 63, wv_ = t >> 6;
    if (lane == 0) red[wv_] = nacc;
    __syncthreads();
    if (t == 0)
      atomicAdd(&nrm[b * C_ + c], red[0] + red[1] + red[2] + red[3]);
  }
}

// ---------------------------------------------------------------------------
// Bilinear 2x upsample 64->128 (unchanged).
// ---------------------------------------------------------------------------
__global__ __launch_bounds__(256) void resize2x_norm(const float* __restrict__ in,
                                                     float* __restrict__ out,
                                                     float* __restrict__ rnq_sum) {
  const int bc = blockIdx.x;
  const int t = threadIdx.x;
  __shared__ float xs[64][65];
  __shared__ float red[4];
  const float* ip = in + (size_t)bc * Ns_;
  for (int p = t; p < 1024; p += 256) {
    float4 v = *(const float4*)&ip[p << 2];
    int r = p >> 4, c0 = (p & 15) << 2;
    xs[r][c0] = v.x; xs[r][c0 + 1] = v.y; xs[r][c0 + 2] = v.z; xs[r][c0 + 3] = v.w;
  }
  __syncthreads();
  float* op = out + (size_t)bc * Nb_;
  float nacc = 0.f;
#pragma unroll
  for (int it = 0; it < 16; ++it) {
    int p = t + it * 256;
    int i = p >> 5;
    int jc = p & 31;
    int ti = i >> 1; bool oi = i & 1;
    int r0 = oi ? ti : (ti > 0 ? ti - 1 : 0);
    int r1 = oi ? (ti < 63 ? ti + 1 : 63) : ti;
    float wr0 = oi ? 0.75f : 0.25f, wr1 = oi ? 0.25f : 0.75f;
    int cb = jc << 1;
    int cm1 = cb > 0 ? cb - 1 : 0;
    int cp2 = cb < 62 ? cb + 2 : 63;
    float a0 = xs[r0][cm1], a1 = xs[r0][cb], a2 = xs[r0][cb + 1], a3 = xs[r0][cp2];
    float b0 = xs[r1][cm1], b1 = xs[r1][cb], b2 = xs[r1][cb + 1], b3 = xs[r1][cp2];
    float ha0 = 0.25f * a0 + 0.75f * a1, hb0 = 0.25f * b0 + 0.75f * b1;
    float ha1 = 0.75f * a1 + 0.25f * a2, hb1 = 0.75f * b1 + 0.25f * b2;
    float ha2 = 0.25f * a1 + 0.75f * a2, hb2 = 0.25f * b1 + 0.75f * b2;
    float ha3 = 0.75f * a2 + 0.25f * a3, hb3 = 0.75f * b2 + 0.25f * b3;
    float4 o = make_float4(wr0 * ha0 + wr1 * hb0, wr0 * ha1 + wr1 * hb1,
                           wr0 * ha2 + wr1 * hb2, wr0 * ha3 + wr1 * hb3);
    *(float4*)&op[p << 2] = o;
    nacc += o.x * o.x + o.y * o.y + o.z * o.z + o.w * o.w;
  }
#pragma unroll
  for (int m = 32; m; m >>= 1) nacc += __shfl_xor(nacc, m, 64);
  int lane = t & 63, wv = t >> 6;
  if (lane == 0) red[wv] = nacc;
  __syncthreads();
  if (t == 0) rnq_sum[bc] = red[0] + red[1] + red[2] + red[3];
}

__global__ void zero_buf(float* __restrict__ p, int n) {
  int i = blockIdx.x * blockDim.x + threadIdx.x;
  if (i < n) p[i] = 0.f;
}

// ---------------------------------------------------------------------------
// Gram (unchanged).
// ---------------------------------------------------------------------------
__global__ __launch_bounds__(256) void gram_qk(const float* __restrict__ q,
                                               const float* __restrict__ k,
                                               float* __restrict__ gram) {
  const int b = blockIdx.z, h = blockIdx.y, sl = blockIdx.x;
  constexpr int NS = Nb_ / 32;
  const int n0 = sl * NS;
  const int t = threadIdx.x;
  const int tc = t >> 4, td = t & 15;
  const float* qb = q + ((size_t)b * C_ + h * CHD_) * Nb_;
  const float* kb = k + ((size_t)b * C_ + h * CHD_) * Nb_;
  __shared__ float qs[32][132];
  __shared__ float kst[128][34];
  float a00 = 0.f, a01 = 0.f, a10 = 0.f, a11 = 0.f;
  for (int nc = 0; nc < NS; nc += 128) {
    for (int i = t; i < 1024; i += 256) {
      int row = i >> 5, nc4 = (i & 31) << 2;
      float4 qv = *(const float4*)&qb[(size_t)row * Nb_ + n0 + nc + nc4];
      *(float4*)&qs[row][nc4] = qv;
      float4 kv = *(const float4*)&kb[(size_t)row * Nb_ + n0 + nc + nc4];
      kst[nc4 + 0][row] = kv.x; kst[nc4 + 1][row] = kv.y;
      kst[nc4 + 2][row] = kv.z; kst[nc4 + 3][row] = kv.w;
    }
    __syncthreads();
#pragma unroll 8
    for (int nn = 0; nn < 128; ++nn) {
      float q0 = qs[2 * tc][nn], q1 = qs[2 * tc + 1][nn];
      float2 kk = *(float2*)&kst[nn][2 * td];
      a00 = fmaf(q0, kk.x, a00); a01 = fmaf(q0, kk.y, a01);
      a10 = fmaf(q1, kk.x, a10); a11 = fmaf(q1, kk.y, a11);
    }
    __syncthreads();
  }
  float* gp = gram + ((size_t)(b * HEADS_ + h) * CHD_ + 2 * tc) * CHD_ + 2 * td;
  atomicAdd(&gp[0], a00);
  atomicAdd(&gp[1], a01);
  atomicAdd(&gp[CHD_], a10);
  atomicAdd(&gp[CHD_ + 1], a11);
}

// ---------------------------------------------------------------------------
// attn softmax (unchanged).
// ---------------------------------------------------------------------------
__global__ __launch_bounds__(1024) void attn_softmax(const float* __restrict__ gram,
                                                     const float* __restrict__ rnq_sum,
                                                     const float* __restrict__ rnk_sum,
                                                     const float* __restrict__ temp,
                                                     float* __restrict__ attn) {
  const int h = blockIdx.x, b = blockIdx.y;
  const int t = threadIdx.x;
  const int c = t >> 5, d = t & 31;
  size_t gi = ((size_t)(b * HEADS_ + h) * CHD_ + c) * CHD_ + d;
  float rq = 1.f / fmaxf(sqrtf(rnq_sum[b * C_ + h * CHD_ + c]), 1e-12f);
  float rk = 1.f / fmaxf(sqrtf(rnk_sum[b * C_ + h * CHD_ + d]), 1e-12f);
  float val = gram[gi] * rq * rk * temp[h];
  float m = val;
#pragma unroll
  for (int s = 16; s; s >>= 1) m = fmaxf(m, __shfl_xor(m, s, 64));
  float e = expf(val - m);
  float ssum = e;
#pragma unroll
  for (int s = 16; s; s >>= 1) ssum += __shfl_xor(ssum, s, 64);
  attn[gi] = e / ssum;
}

// ---------------------------------------------------------------------------
// Fused attn@v + proj (unchanged).
// ---------------------------------------------------------------------------
__global__ __launch_bounds__(256) void av_proj(const float* __restrict__ attn,
                                               const float* __restrict__ v,
                                               const float* __restrict__ p_bw,
                                               const float* __restrict__ p_bs,
                                               const float* __restrict__ p_ww,
                                               const float* __restrict__ p_ws,
                                               float* __restrict__ out) {
  const int bh = blockIdx.y;
  const int b = bh >> 3, h = bh & 7;
  const int half = threadIdx.x >> 7;
  const int pl = threadIdx.x & 127;
  const int p = blockIdx.x * 128 + pl;
  const int bi = p >> 6, bj = p & 63;
  __shared__ float at[32][36];
  for (int i = threadIdx.x; i < 1024; i += 256)
    at[i & 31][i >> 5] = attn[(size_t)bh * 1024 + i];
  __syncthreads();
  const float* vb = v + ((size_t)b * C_ + h * CHD_) * Nb_;
  const int n00 = (2 * bi) * Wb_ + 2 * bj;
  float acc[16][4] = {};
  for (int d = 0; d < 32; ++d) {
    const float* vp = vb + (size_t)d * Nb_ + n00;
    float2 vt = *(const float2*)vp;
    float2 vbt = *(const float2*)(vp + Wb_);
    float4 a0 = *(float4*)&at[d][half * 16];
    float4 a1 = *(float4*)&at[d][half * 16 + 4];
    float4 a2 = *(float4*)&at[d][half * 16 + 8];
    float4 a3 = *(float4*)&at[d][half * 16 + 12];
    float av[16] = {a0.x, a0.y, a0.z, a0.w, a1.x, a1.y, a1.z, a1.w,
                    a2.x, a2.y, a2.z, a2.w, a3.x, a3.y, a3.z, a3.w};
#pragma unroll
    for (int cc = 0; cc < 16; ++cc) {
      acc[cc][0] = fmaf(av[cc], vt.x,  acc[cc][0]);
      acc[cc][1] = fmaf(av[cc], vt.y,  acc[cc][1]);
      acc[cc][2] = fmaf(av[cc], vbt.x, acc[cc][2]);
      acc[cc][3] = fmaf(av[cc], vbt.y, acc[cc][3]);
    }
  }
  float* ob = out + ((size_t)b * C_ + h * CHD_) * Nb_;
#pragma unroll
  for (int cc = 0; cc < 16; ++cc) {
    int lc = half * 16 + cc;
    int gc = h * CHD_ + lc;
    float p00 = acc[cc][0], p01 = acc[cc][1], p10 = acc[cc][2], p11 = acc[cc][3];
    float ll = 0.5f * (p00 + p01 + p10 + p11) * (p_ww[gc * 4 + 0] * p_ws[gc * 4 + 0]);
    float hl = 0.5f * (p00 + p01 - p10 - p11) * (p_ww[gc * 4 + 1] * p_ws[gc * 4 + 1]);
    float lh = 0.5f * (p00 - p01 + p10 - p11) * (p_ww[gc * 4 + 2] * p_ws[gc * 4 + 2]);
    float hh = 0.5f * (p00 - p01 - p10 + p11) * (p_ww[gc * 4 + 3] * p_ws[gc * 4 + 3]);
    float bb = p_bw[gc] * p_bs[gc];
    float* op = ob + (size_t)lc * Nb_ + n00;
    *(float2*)op         = make_float2(p00 * bb + 0.5f * (ll + hl + lh + hh),
                                       p01 * bb + 0.5f * (ll + hl - lh - hh));
    *(float2*)(op + Wb_) = make_float2(p10 * bb + 0.5f * (ll - hl + lh - hh),
                                       p11 * bb + 0.5f * (ll - hl - lh + hh));
  }
}

// ---------------------------------------------------------------------------
extern "C" void kernel_launch(void* const* d_in, const int* in_sizes, int n_in,
                              void* d_out, int out_size, void* d_ws, size_t ws_size,
                              hipStream_t stream) {
  const float* x    = (const float*)d_in[0];
  const float* cf   = (const float*)d_in[1];
  const float* Wq   = (const float*)d_in[2];
  const float* Wk   = (const float*)d_in[3];
  const float* Wv   = (const float*)d_in[4];
  const float* temp = (const float*)d_in[5];
  const float* q_bw = (const float*)d_in[6];
  const float* q_bs = (const float*)d_in[7];
  const float* q_ww = (const float*)d_in[8];
  const float* q_ws = (const float*)d_in[9];
  const float* k_bw = (const float*)d_in[10];
  const float* k_bs = (const float*)d_in[11];
  const float* k_ww = (const float*)d_in[12];
  const float* k_ws = (const float*)d_in[13];
  const float* v_bw = (const float*)d_in[14];
  const float* v_bs = (const float*)d_in[15];
  const float* v_ww = (const float*)d_in[16];
  const float* v_ws = (const float*)d_in[17];
  const float* p_bw = (const float*)d_in[18];
  const float* p_bs = (const float*)d_in[19];
  const float* p_ww = (const float*)d_in[20];
  const float* p_ws = (const float*)d_in[21];

  // Workspace (float-word offsets). ~194 MB total.
  float* ws   = (float*)d_ws;
  float* A    = ws;                 // q0 [2,256,64,64]      2,097,152
  float* Bb   = A  + 2097152;       // k0 -> q_up            8,388,608
  float* Cb   = Bb + 8388608;       // v0                    8,388,608
  float* Fb   = Cb + 8388608;       // q1 [2,256,64,64]      2,097,152
  float* Gb   = Fb + 2097152;       // k1                    8,388,608
  float* Hb   = Gb + 8388608;       // v1                    8,388,608
  float* XhKf = Hb + 8388608;       // cf hi bf16 [2,16384,256]  4,194,304 fw
  float* XlKf = XhKf + 4194304;     // cf lo                     4,194,304 fw
  float* Xhxf = XlKf + 4194304;     // x hi [2,4096,256]         1,048,576 fw
  float* Xlxf = Xhxf + 1048576;     // x lo                      1,048,576 fw
  float* Wpf  = Xlxf + 1048576;     // W hi/lo packed            196,608 fw
  float* rnq  = Wpf + 196608;       // 512 (direct write)
  float* rnk  = rnq + 512;          // 512 (atomic)
  float* gram = rnk + 512;          // 16384 (atomic)
  float* attn = gram + 16384;       // 16384
  unsigned short* XhK = (unsigned short*)XhKf;
  unsigned short* XlK = (unsigned short*)XlKf;
  unsigned short* Xhx = (unsigned short*)Xhxf;
  unsigned short* Xlx = (unsigned short*)Xlxf;
  unsigned short* Wp  = (unsigned short*)Wpf;
  // Wp layout (ushort idx): WqH 0, WqL 65536, WkH 131072, WkL 196608,
  //                         WvH 262144, WvL 327680

  // 0) zero the atomic accumulators (rnk|gram contiguous = 16896 floats)
  zero_buf<<<(16896 + 255) / 256, 256, 0, stream>>>(rnk, 16896);

  // 1) split+transpose inputs, split weights
  cvt_split_T<<<dim3(Nb_ / 64, C_ / 64, B_), 256, 0, stream>>>(cf, XhK, XlK, Nb_);
  cvt_split_T<<<dim3(Ns_ / 64, C_ / 64, B_), 256, 0, stream>>>(x,  Xhx, Xlx, Ns_);
  cvt_w<<<3 * 65536 / 256, 256, 0, stream>>>(Wq, Wk, Wv, Wp);

  // 2) MFMA GEMMs: q single, k/v dual
  gemm_mfma<false><<<dim3(Ns_ / 64, C_ / 64, B_), 256, 0, stream>>>(
      Xhx, Xlx, Wp, Wp + 65536, nullptr, nullptr, A, nullptr, Ns_);
  gemm_mfma<true><<<dim3(Nb_ / 64, C_ / 64, B_), 256, 0, stream>>>(
      XhK, XlK, Wp + 131072, Wp + 196608, Wp + 262144, Wp + 327680, Bb, Cb, Nb_);

  // 3) fused wtconv: q (64x64), k (128x128, +norm fold), v (128x128)
  wtconv_fused<64><<<dim3(1, C_, B_), 256, 0, stream>>>(A, q_bw, q_bs, q_ww, q_ws, Fb, nullptr);
  wtconv_fused<128><<<dim3(4, C_, B_), 256, 0, stream>>>(Bb, k_bw, k_bs, k_ww, k_ws, Gb, rnk);
  wtconv_fused<128><<<dim3(4, C_, B_), 256, 0, stream>>>(Cb, v_bw, v_bs, v_ww, v_ws, Hb, nullptr);

  // 4) upsample q1 -> q_up (into Bb; k0 dead) + rnq direct
  resize2x_norm<<<B_ * C_, 256, 0, stream>>>(Fb, Bb, rnq);

  // 5) gram + softmax
  gram_qk<<<dim3(32, HEADS_, B_), 256, 0, stream>>>(Bb, Gb, gram);
  attn_softmax<<<dim3(HEADS_, B_), 1024, 0, stream>>>(gram, rnq, rnk, temp, attn);

  // 6) fused attn@v + proj -> d_out
  av_proj<<<dim3(Nb_ / 4 / 128, B_ * HEADS_), 256, 0, stream>>>(
      attn, Hb, p_bw, p_bs, p_ww, p_ws, (float*)d_out);
}

// Round 10
// 280.251 us; speedup vs baseline: 1.4292x; 1.0228x over previous
//
#include <hip/hip_runtime.h>
#include <math.h>

// WaveletAtt: B=2, CIN=DIM=256, HEADS=8, wt_levels=1 Haar
constexpr int B_ = 2;
constexpr int C_ = 256;
constexpr int Hb_ = 128, Wb_ = 128;      // crossFeat / k / v / output spatial
constexpr int Nb_ = Hb_ * Wb_;           // 16384
constexpr int Hs_ = 64, Ws_ = 64;        // x / q spatial
constexpr int Ns_ = Hs_ * Ws_;           // 4096
constexpr int HEADS_ = 8;
constexpr int CHD_ = C_ / HEADS_;        // 32

typedef float f32x4 __attribute__((ext_vector_type(4)));
typedef short bf16x8 __attribute__((ext_vector_type(8)));          // 8 bf16 = 4 VGPR
typedef unsigned short u16x8 __attribute__((ext_vector_type(8)));  // 16B vector

// f32 -> bf16(hi) + bf16(lo), RNE both. x ≈ hi + lo, residual ~2^-18 rel.
__device__ inline void cvt_split(float f, unsigned short& h, unsigned short& l) {
  unsigned u = __float_as_uint(f);
  unsigned r = u + 0x7fffu + ((u >> 16) & 1u);
  h = (unsigned short)(r >> 16);
  float hf = __uint_as_float((unsigned)h << 16);
  float lo = f - hf;
  unsigned u2 = __float_as_uint(lo);
  unsigned r2 = u2 + 0x7fffu + ((u2 >> 16) & 1u);
  l = (unsigned short)(r2 >> 16);
}

// ---------------------------------------------------------------------------
// Split+transpose: X f32 [b][C][NTOT] -> Xh,Xl bf16-bits [b][NTOT][C]
// ---------------------------------------------------------------------------
__global__ __launch_bounds__(256) void cvt_split_T(const float* __restrict__ X,
                                                   unsigned short* __restrict__ Xh,
                                                   unsigned short* __restrict__ Xl,
                                                   int NTOT) {
  __shared__ float xs[64][72];
  const int b  = blockIdx.z;
  const int c0 = blockIdx.y * 64;
  const int n0 = blockIdx.x * 64;
  const int t  = threadIdx.x;
  const float* xb = X + ((size_t)(b * C_ + c0)) * NTOT + n0;
  {
    int cl = t >> 4, n4 = (t & 15) << 2;
#pragma unroll
    for (int i = 0; i < 4; ++i) {
      float4 v = *(const float4*)(xb + (size_t)(cl + 16 * i) * NTOT + n4);
      *(float4*)&xs[cl + 16 * i][n4] = v;
    }
  }
  __syncthreads();
  const int n_l = t >> 2, cqb = t & 3;
  size_t obase = ((size_t)b * NTOT + n0 + n_l) * C_ + c0;
#pragma unroll
  for (int it = 0; it < 2; ++it) {
    int cq = it * 4 + cqb;
    u16x8 hv, lv;
#pragma unroll
    for (int j = 0; j < 8; ++j) {
      unsigned short h, l;
      cvt_split(xs[cq * 8 + j][n_l], h, l);
      hv[j] = h; lv[j] = l;
    }
    *(u16x8*)(Xh + obase + cq * 8) = hv;
    *(u16x8*)(Xl + obase + cq * 8) = lv;
  }
}

// Split Wq|Wk|Wv [o][c] f32 -> packed hi/lo bf16 planes.
__global__ void cvt_w(const float* __restrict__ Wq, const float* __restrict__ Wk,
                      const float* __restrict__ Wv, unsigned short* __restrict__ Wp) {
  int i = blockIdx.x * 256 + threadIdx.x;
  int m = i >> 16, idx = i & 65535;
  const float* src = (m == 0) ? Wq : (m == 1) ? Wk : Wv;
  unsigned short h, l;
  cvt_split(src[idx], h, l);
  Wp[(size_t)m * 131072 + idx] = h;
  Wp[(size_t)m * 131072 + 65536 + idx] = l;
}

// ---------------------------------------------------------------------------
// MFMA GEMM v2: block 64(o) x 128(n), 4 waves, 8 subtiles/wave.
// Flat LDS layout slot(n,kO)=n*4+kO (16B slots): staged writes AND B-reads are
// contiguous 1024B per wave => conflict-free. Double-buffered, ONE barrier
// per K-step; next-tile global loads issue before MFMA block, LDS writes after.
// ---------------------------------------------------------------------------
template<bool DUAL>
__global__ __launch_bounds__(256) void gemm_mfma(
    const unsigned short* __restrict__ XhT, const unsigned short* __restrict__ XlT,
    const unsigned short* __restrict__ Wh1, const unsigned short* __restrict__ Wl1,
    const unsigned short* __restrict__ Wh2, const unsigned short* __restrict__ Wl2,
    float* __restrict__ out1, float* __restrict__ out2, int NTOT) {
  __shared__ __align__(16) unsigned short XhL[2][128 * 32];   // 8KB per buffer
  __shared__ __align__(16) unsigned short XlL[2][128 * 32];
  const int b  = blockIdx.z;
  const int o0 = blockIdx.y * 64;
  const int n0 = blockIdx.x * 128;
  const int t  = threadIdx.x;
  const int w = t >> 6, lane = t & 63;
  const int lr = lane & 15, lk = lane >> 4;
  const unsigned short* xh = XhT + ((size_t)b * NTOT + n0) * C_;
  const unsigned short* xl = XlT + ((size_t)b * NTOT + n0) * C_;
  const int arow = o0 + w * 16 + lr;
  const size_t abase = (size_t)arow * C_ + lk * 8;
  // staging: thread t owns slots t and t+256; slot s -> n=s>>2, kO=s&3
  const size_t g0 = (size_t)(t >> 2) * C_ + (size_t)(t & 3) * 8;
  const size_t g1 = (size_t)((t >> 2) + 64) * C_ + (size_t)(t & 3) * 8;
  f32x4 acc1[8] = {};
  f32x4 acc2[8] = {};
  // prologue: stage tile 0, load A frags for step 0
  *(u16x8*)&XhL[0][t * 8]         = *(const u16x8*)(xh + g0);
  *(u16x8*)&XhL[0][(t + 256) * 8] = *(const u16x8*)(xh + g1);
  *(u16x8*)&XlL[0][t * 8]         = *(const u16x8*)(xl + g0);
  *(u16x8*)&XlL[0][(t + 256) * 8] = *(const u16x8*)(xl + g1);
  bf16x8 a1h = *(const bf16x8*)(Wh1 + abase);
  bf16x8 a1l = *(const bf16x8*)(Wl1 + abase);
  bf16x8 a2h = {}, a2l = {};
  if constexpr (DUAL) {
    a2h = *(const bf16x8*)(Wh2 + abase);
    a2l = *(const bf16x8*)(Wl2 + abase);
  }
  __syncthreads();
  for (int step = 0; step < 8; ++step) {
    const int cur = step & 1;
    u16x8 xr0h, xr1h, xr0l, xr1l;
    bf16x8 n1h = {}, n1l = {}, n2h = {}, n2l = {};
    const int c1 = (step + 1) * 32;
    if (step < 7) {   // issue next-tile loads EARLY (latency hides under MFMA)
      xr0h = *(const u16x8*)(xh + g0 + c1);
      xr1h = *(const u16x8*)(xh + g1 + c1);
      xr0l = *(const u16x8*)(xl + g0 + c1);
      xr1l = *(const u16x8*)(xl + g1 + c1);
      n1h = *(const bf16x8*)(Wh1 + abase + c1);
      n1l = *(const bf16x8*)(Wl1 + abase + c1);
      if constexpr (DUAL) {
        n2h = *(const bf16x8*)(Wh2 + abase + c1);
        n2l = *(const bf16x8*)(Wl2 + abase + c1);
      }
    }
#pragma unroll
    for (int s = 0; s < 8; ++s) {
      const int bo = ((s * 16 + lr) * 4 + lk) * 8;
      bf16x8 bh = *(const bf16x8*)&XhL[cur][bo];
      bf16x8 bl = *(const bf16x8*)&XlL[cur][bo];
      acc1[s] = __builtin_amdgcn_mfma_f32_16x16x32_bf16(a1h, bh, acc1[s], 0, 0, 0);
      acc1[s] = __builtin_amdgcn_mfma_f32_16x16x32_bf16(a1h, bl, acc1[s], 0, 0, 0);
      acc1[s] = __builtin_amdgcn_mfma_f32_16x16x32_bf16(a1l, bh, acc1[s], 0, 0, 0);
      if constexpr (DUAL) {
        acc2[s] = __builtin_amdgcn_mfma_f32_16x16x32_bf16(a2h, bh, acc2[s], 0, 0, 0);
        acc2[s] = __builtin_amdgcn_mfma_f32_16x16x32_bf16(a2h, bl, acc2[s], 0, 0, 0);
        acc2[s] = __builtin_amdgcn_mfma_f32_16x16x32_bf16(a2l, bh, acc2[s], 0, 0, 0);
      }
    }
    if (step < 7) {   // write staged regs -> other buffer (late)
      const int nxt = cur ^ 1;
      *(u16x8*)&XhL[nxt][t * 8]         = xr0h;
      *(u16x8*)&XhL[nxt][(t + 256) * 8] = xr1h;
      *(u16x8*)&XlL[nxt][t * 8]         = xr0l;
      *(u16x8*)&XlL[nxt][(t + 256) * 8] = xr1l;
      a1h = n1h; a1l = n1l;
      if constexpr (DUAL) { a2h = n2h; a2l = n2l; }
    }
    __syncthreads();
  }
  // epilogue: D row = lk*4+r, col = s*16+lr (m89-verified C/D mapping)
  float* o1 = out1 + ((size_t)(b * C_ + o0 + w * 16)) * NTOT + n0;
#pragma unroll
  for (int s = 0; s < 8; ++s)
#pragma unroll
    for (int r = 0; r < 4; ++r)
      o1[(size_t)(lk * 4 + r) * NTOT + s * 16 + lr] = acc1[s][r];
  if constexpr (DUAL) {
    float* o2 = out2 + ((size_t)(b * C_ + o0 + w * 16)) * NTOT + n0;
#pragma unroll
    for (int s = 0; s < 8; ++s)
#pragma unroll
      for (int r = 0; r < 4; ++r)
        o2[(size_t)(lk * 4 + r) * NTOT + s * 16 + lr] = acc2[s][r];
  }
}

// ---------------------------------------------------------------------------
// Fused WTConv (unchanged, known-correct).
// ---------------------------------------------------------------------------
template<int HP>
__global__ __launch_bounds__(256) void wtconv_fused(
    const float* __restrict__ x, const float* __restrict__ bw,
    const float* __restrict__ bs, const float* __restrict__ ww,
    const float* __restrict__ wsc, float* __restrict__ out,
    float* __restrict__ nrm) {
  constexpr int NT = HP / 64;
  const int tile = blockIdx.x;
  const int c = blockIdx.y, b = blockIdx.z;
  const int oy = (tile / NT) * 64, ox = (tile % NT) * 64;
  const float* xp = x + ((size_t)(b * C_) + c) * HP * HP;

  __shared__ float xt[68][76];
  __shared__ f32x4 sb4[34][36];
  __shared__ float red[4];

  float wb[9];
#pragma unroll
  for (int i = 0; i < 9; ++i) wb[i] = bw[c * 9 + i];
  const float sbase = bs[c];
  f32x4 wv4[9]; f32x4 sv4;
#pragma unroll
  for (int i = 0; i < 9; ++i) {
    wv4[i].x = ww[(c * 4 + 0) * 9 + i];
    wv4[i].y = ww[(c * 4 + 1) * 9 + i];
    wv4[i].z = ww[(c * 4 + 2) * 9 + i];
    wv4[i].w = ww[(c * 4 + 3) * 9 + i];
  }
  sv4.x = wsc[c * 4 + 0]; sv4.y = wsc[c * 4 + 1];
  sv4.z = wsc[c * 4 + 2]; sv4.w = wsc[c * 4 + 3];

  const int t = threadIdx.x;
  for (int p = t; p < 68 * 18; p += 256) {
    int r = p / 18, k4 = (p % 18) << 2;
    int gy = oy - 2 + r, gx = ox - 4 + k4;
    float4 v = make_float4(0.f, 0.f, 0.f, 0.f);
    if ((unsigned)gy < (unsigned)HP && (unsigned)gx < (unsigned)HP)
      v = *(const float4*)(xp + (size_t)gy * HP + gx);
    *(float4*)&xt[r][k4] = v;
  }
  __syncthreads();
  for (int p = t; p < 34 * 34; p += 256) {
    int i = p / 34, j = p % 34;
    float p00 = xt[2 * i][2 * j + 2],     p01 = xt[2 * i][2 * j + 3];
    float p10 = xt[2 * i + 1][2 * j + 2], p11 = xt[2 * i + 1][2 * j + 3];
    f32x4 s;
    s.x = 0.5f * (p00 + p01 + p10 + p11);
    s.y = 0.5f * (p00 + p01 - p10 - p11);
    s.z = 0.5f * (p00 - p01 + p10 - p11);
    s.w = 0.5f * (p00 - p01 - p10 + p11);
    sb4[i][j] = s;
  }
  __syncthreads();

  float nacc = 0.f;
  float* op0 = out + ((size_t)(b * C_) + c) * HP * HP;
  for (int p = t; p < 32 * 32; p += 256) {
    int i = p >> 5, j = p & 31;
    f32x4 a4 = {0.f, 0.f, 0.f, 0.f};
#pragma unroll
    for (int dh = 0; dh < 3; ++dh)
#pragma unroll
      for (int dw = 0; dw < 3; ++dw)
        a4 += sb4[i + dh][j + dw] * wv4[dh * 3 + dw];
    f32x4 s4 = a4 * sv4;
    float pp[4][4];
#pragma unroll
    for (int r = 0; r < 4; ++r)
#pragma unroll
      for (int cc = 0; cc < 4; ++cc)
        pp[r][cc] = xt[2 * i + 1 + r][2 * j + 3 + cc];
    float o4[2][2];
#pragma unroll
    for (int di = 0; di < 2; ++di)
#pragma unroll
      for (int dj = 0; dj < 2; ++dj) {
        float a = 0.f;
#pragma unroll
        for (int dh = 0; dh < 3; ++dh)
#pragma unroll
          for (int dw = 0; dw < 3; ++dw)
            a = fmaf(pp[di + dh][dj + dw], wb[dh * 3 + dw], a);
        a *= sbase;
        float s1 = di ? -s4.y : s4.y;
        float s2 = dj ? -s4.z : s4.z;
        float s3 = (di ^ dj) ? -s4.w : s4.w;
        o4[di][dj] = a + 0.5f * (s4.x + s1 + s2 + s3);
      }
    float* op = op0 + (size_t)(oy + 2 * i) * HP + ox + 2 * j;
    *(float2*)op        = make_float2(o4[0][0], o4[0][1]);
    *(float2*)(op + HP) = make_float2(o4[1][0], o4[1][1]);
    nacc += o4[0][0] * o4[0][0] + o4[0][1] * o4[0][1] +
            o4[1][0] * o4[1][0] + o4[1][1] * o4[1][1];
  }
  if (nrm != nullptr) {
#pragma unroll
    for (int m = 32; m; m >>= 1) nacc += __shfl_xor(nacc, m, 64);
    int lane = t & 63, wv_ = t >> 6;
    if (lane == 0) red[wv_] = nacc;
    __syncthreads();
    if (t == 0)
      atomicAdd(&nrm[b * C_ + c], red[0] + red[1] + red[2] + red[3]);
  }
}

// ---------------------------------------------------------------------------
// Bilinear 2x upsample 64->128 (unchanged).
// ---------------------------------------------------------------------------
__global__ __launch_bounds__(256) void resize2x_norm(const float* __restrict__ in,
                                                     float* __restrict__ out,
                                                     float* __restrict__ rnq_sum) {
  const int bc = blockIdx.x;
  const int t = threadIdx.x;
  __shared__ float xs[64][65];
  __shared__ float red[4];
  const float* ip = in + (size_t)bc * Ns_;
  for (int p = t; p < 1024; p += 256) {
    float4 v = *(const float4*)&ip[p << 2];
    int r = p >> 4, c0 = (p & 15) << 2;
    xs[r][c0] = v.x; xs[r][c0 + 1] = v.y; xs[r][c0 + 2] = v.z; xs[r][c0 + 3] = v.w;
  }
  __syncthreads();
  float* op = out + (size_t)bc * Nb_;
  float nacc = 0.f;
#pragma unroll
  for (int it = 0; it < 16; ++it) {
    int p = t + it * 256;
    int i = p >> 5;
    int jc = p & 31;
    int ti = i >> 1; bool oi = i & 1;
    int r0 = oi ? ti : (ti > 0 ? ti - 1 : 0);
    int r1 = oi ? (ti < 63 ? ti + 1 : 63) : ti;
    float wr0 = oi ? 0.75f : 0.25f, wr1 = oi ? 0.25f : 0.75f;
    int cb = jc << 1;
    int cm1 = cb > 0 ? cb - 1 : 0;
    int cp2 = cb < 62 ? cb + 2 : 63;
    float a0 = xs[r0][cm1], a1 = xs[r0][cb], a2 = xs[r0][cb + 1], a3 = xs[r0][cp2];
    float b0 = xs[r1][cm1], b1 = xs[r1][cb], b2 = xs[r1][cb + 1], b3 = xs[r1][cp2];
    float ha0 = 0.25f * a0 + 0.75f * a1, hb0 = 0.25f * b0 + 0.75f * b1;
    float ha1 = 0.75f * a1 + 0.25f * a2, hb1 = 0.75f * b1 + 0.25f * b2;
    float ha2 = 0.25f * a1 + 0.75f * a2, hb2 = 0.25f * b1 + 0.75f * b2;
    float ha3 = 0.75f * a2 + 0.25f * a3, hb3 = 0.75f * b2 + 0.25f * b3;
    float4 o = make_float4(wr0 * ha0 + wr1 * hb0, wr0 * ha1 + wr1 * hb1,
                           wr0 * ha2 + wr1 * hb2, wr0 * ha3 + wr1 * hb3);
    *(float4*)&op[p << 2] = o;
    nacc += o.x * o.x + o.y * o.y + o.z * o.z + o.w * o.w;
  }
#pragma unroll
  for (int m = 32; m; m >>= 1) nacc += __shfl_xor(nacc, m, 64);
  int lane = t & 63, wv = t >> 6;
  if (lane == 0) red[wv] = nacc;
  __syncthreads();
  if (t == 0) rnq_sum[bc] = red[0] + red[1] + red[2] + red[3];
}

__global__ void zero_buf(float* __restrict__ p, int n) {
  int i = blockIdx.x * blockDim.x + threadIdx.x;
  if (i < n) p[i] = 0.f;
}

// ---------------------------------------------------------------------------
// Gram (unchanged).
// ---------------------------------------------------------------------------
__global__ __launch_bounds__(256) void gram_qk(const float* __restrict__ q,
                                               const float* __restrict__ k,
                                               float* __restrict__ gram) {
  const int b = blockIdx.z, h = blockIdx.y, sl = blockIdx.x;
  constexpr int NS = Nb_ / 32;
  const int n0 = sl * NS;
  const int t = threadIdx.x;
  const int tc = t >> 4, td = t & 15;
  const float* qb = q + ((size_t)b * C_ + h * CHD_) * Nb_;
  const float* kb = k + ((size_t)b * C_ + h * CHD_) * Nb_;
  __shared__ float qs[32][132];
  __shared__ float kst[128][34];
  float a00 = 0.f, a01 = 0.f, a10 = 0.f, a11 = 0.f;
  for (int nc = 0; nc < NS; nc += 128) {
    for (int i = t; i < 1024; i += 256) {
      int row = i >> 5, nc4 = (i & 31) << 2;
      float4 qv = *(const float4*)&qb[(size_t)row * Nb_ + n0 + nc + nc4];
      *(float4*)&qs[row][nc4] = qv;
      float4 kv = *(const float4*)&kb[(size_t)row * Nb_ + n0 + nc + nc4];
      kst[nc4 + 0][row] = kv.x; kst[nc4 + 1][row] = kv.y;
      kst[nc4 + 2][row] = kv.z; kst[nc4 + 3][row] = kv.w;
    }
    __syncthreads();
#pragma unroll 8
    for (int nn = 0; nn < 128; ++nn) {
      float q0 = qs[2 * tc][nn], q1 = qs[2 * tc + 1][nn];
      float2 kk = *(float2*)&kst[nn][2 * td];
      a00 = fmaf(q0, kk.x, a00); a01 = fmaf(q0, kk.y, a01);
      a10 = fmaf(q1, kk.x, a10); a11 = fmaf(q1, kk.y, a11);
    }
    __syncthreads();
  }
  float* gp = gram + ((size_t)(b * HEADS_ + h) * CHD_ + 2 * tc) * CHD_ + 2 * td;
  atomicAdd(&gp[0], a00);
  atomicAdd(&gp[1], a01);
  atomicAdd(&gp[CHD_], a10);
  atomicAdd(&gp[CHD_ + 1], a11);
}

// ---------------------------------------------------------------------------
// attn softmax (unchanged).
// ---------------------------------------------------------------------------
__global__ __launch_bounds__(1024) void attn_softmax(const float* __restrict__ gram,
                                                     const float* __restrict__ rnq_sum,
                                                     const float* __restrict__ rnk_sum,
                                                     const float* __restrict__ temp,
                                                     float* __restrict__ attn) {
  const int h = blockIdx.x, b = blockIdx.y;
  const int t = threadIdx.x;
  const int c = t >> 5, d = t & 31;
  size_t gi = ((size_t)(b * HEADS_ + h) * CHD_ + c) * CHD_ + d;
  float rq = 1.f / fmaxf(sqrtf(rnq_sum[b * C_ + h * CHD_ + c]), 1e-12f);
  float rk = 1.f / fmaxf(sqrtf(rnk_sum[b * C_ + h * CHD_ + d]), 1e-12f);
  float val = gram[gi] * rq * rk * temp[h];
  float m = val;
#pragma unroll
  for (int s = 16; s; s >>= 1) m = fmaxf(m, __shfl_xor(m, s, 64));
  float e = expf(val - m);
  float ssum = e;
#pragma unroll
  for (int s = 16; s; s >>= 1) ssum += __shfl_xor(ssum, s, 64);
  attn[gi] = e / ssum;
}

// ---------------------------------------------------------------------------
// Fused attn@v + proj (unchanged).
// ---------------------------------------------------------------------------
__global__ __launch_bounds__(256) void av_proj(const float* __restrict__ attn,
                                               const float* __restrict__ v,
                                               const float* __restrict__ p_bw,
                                               const float* __restrict__ p_bs,
                                               const float* __restrict__ p_ww,
                                               const float* __restrict__ p_ws,
                                               float* __restrict__ out) {
  const int bh = blockIdx.y;
  const int b = bh >> 3, h = bh & 7;
  const int half = threadIdx.x >> 7;
  const int pl = threadIdx.x & 127;
  const int p = blockIdx.x * 128 + pl;
  const int bi = p >> 6, bj = p & 63;
  __shared__ float at[32][36];
  for (int i = threadIdx.x; i < 1024; i += 256)
    at[i & 31][i >> 5] = attn[(size_t)bh * 1024 + i];
  __syncthreads();
  const float* vb = v + ((size_t)b * C_ + h * CHD_) * Nb_;
  const int n00 = (2 * bi) * Wb_ + 2 * bj;
  float acc[16][4] = {};
  for (int d = 0; d < 32; ++d) {
    const float* vp = vb + (size_t)d * Nb_ + n00;
    float2 vt = *(const float2*)vp;
    float2 vbt = *(const float2*)(vp + Wb_);
    float4 a0 = *(float4*)&at[d][half * 16];
    float4 a1 = *(float4*)&at[d][half * 16 + 4];
    float4 a2 = *(float4*)&at[d][half * 16 + 8];
    float4 a3 = *(float4*)&at[d][half * 16 + 12];
    float av[16] = {a0.x, a0.y, a0.z, a0.w, a1.x, a1.y, a1.z, a1.w,
                    a2.x, a2.y, a2.z, a2.w, a3.x, a3.y, a3.z, a3.w};
#pragma unroll
    for (int cc = 0; cc < 16; ++cc) {
      acc[cc][0] = fmaf(av[cc], vt.x,  acc[cc][0]);
      acc[cc][1] = fmaf(av[cc], vt.y,  acc[cc][1]);
      acc[cc][2] = fmaf(av[cc], vbt.x, acc[cc][2]);
      acc[cc][3] = fmaf(av[cc], vbt.y, acc[cc][3]);
    }
  }
  float* ob = out + ((size_t)b * C_ + h * CHD_) * Nb_;
#pragma unroll
  for (int cc = 0; cc < 16; ++cc) {
    int lc = half * 16 + cc;
    int gc = h * CHD_ + lc;
    float p00 = acc[cc][0], p01 = acc[cc][1], p10 = acc[cc][2], p11 = acc[cc][3];
    float ll = 0.5f * (p00 + p01 + p10 + p11) * (p_ww[gc * 4 + 0] * p_ws[gc * 4 + 0]);
    float hl = 0.5f * (p00 + p01 - p10 - p11) * (p_ww[gc * 4 + 1] * p_ws[gc * 4 + 1]);
    float lh = 0.5f * (p00 - p01 + p10 - p11) * (p_ww[gc * 4 + 2] * p_ws[gc * 4 + 2]);
    float hh = 0.5f * (p00 - p01 - p10 + p11) * (p_ww[gc * 4 + 3] * p_ws[gc * 4 + 3]);
    float bb = p_bw[gc] * p_bs[gc];
    float* op = ob + (size_t)lc * Nb_ + n00;
    *(float2*)op         = make_float2(p00 * bb + 0.5f * (ll + hl + lh + hh),
                                       p01 * bb + 0.5f * (ll + hl - lh - hh));
    *(float2*)(op + Wb_) = make_float2(p10 * bb + 0.5f * (ll - hl + lh - hh),
                                       p11 * bb + 0.5f * (ll - hl - lh + hh));
  }
}

// ---------------------------------------------------------------------------
extern "C" void kernel_launch(void* const* d_in, const int* in_sizes, int n_in,
                              void* d_out, int out_size, void* d_ws, size_t ws_size,
                              hipStream_t stream) {
  const float* x    = (const float*)d_in[0];
  const float* cf   = (const float*)d_in[1];
  const float* Wq   = (const float*)d_in[2];
  const float* Wk   = (const float*)d_in[3];
  const float* Wv   = (const float*)d_in[4];
  const float* temp = (const float*)d_in[5];
  const float* q_bw = (const float*)d_in[6];
  const float* q_bs = (const float*)d_in[7];
  const float* q_ww = (const float*)d_in[8];
  const float* q_ws = (const float*)d_in[9];
  const float* k_bw = (const float*)d_in[10];
  const float* k_bs = (const float*)d_in[11];
  const float* k_ww = (const float*)d_in[12];
  const float* k_ws = (const float*)d_in[13];
  const float* v_bw = (const float*)d_in[14];
  const float* v_bs = (const float*)d_in[15];
  const float* v_ww = (const float*)d_in[16];
  const float* v_ws = (const float*)d_in[17];
  const float* p_bw = (const float*)d_in[18];
  const float* p_bs = (const float*)d_in[19];
  const float* p_ww = (const float*)d_in[20];
  const float* p_ws = (const float*)d_in[21];

  // Workspace (float-word offsets). ~194 MB total.
  float* ws   = (float*)d_ws;
  float* A    = ws;                 // q0 [2,256,64,64]      2,097,152
  float* Bb   = A  + 2097152;       // k0 -> q_up            8,388,608
  float* Cb   = Bb + 8388608;       // v0                    8,388,608
  float* Fb   = Cb + 8388608;       // q1 [2,256,64,64]      2,097,152
  float* Gb   = Fb + 2097152;       // k1                    8,388,608
  float* Hb   = Gb + 8388608;       // v1                    8,388,608
  float* XhKf = Hb + 8388608;       // cf hi bf16 [2,16384,256]  4,194,304 fw
  float* XlKf = XhKf + 4194304;     // cf lo                     4,194,304 fw
  float* Xhxf = XlKf + 4194304;     // x hi [2,4096,256]         1,048,576 fw
  float* Xlxf = Xhxf + 1048576;     // x lo                      1,048,576 fw
  float* Wpf  = Xlxf + 1048576;     // W hi/lo packed            196,608 fw
  float* rnq  = Wpf + 196608;       // 512 (direct write)
  float* rnk  = rnq + 512;          // 512 (atomic)
  float* gram = rnk + 512;          // 16384 (atomic)
  float* attn = gram + 16384;       // 16384
  unsigned short* XhK = (unsigned short*)XhKf;
  unsigned short* XlK = (unsigned short*)XlKf;
  unsigned short* Xhx = (unsigned short*)Xhxf;
  unsigned short* Xlx = (unsigned short*)Xlxf;
  unsigned short* Wp  = (unsigned short*)Wpf;
  // Wp layout (ushort idx): WqH 0, WqL 65536, WkH 131072, WkL 196608,
  //                         WvH 262144, WvL 327680

  // 0) zero the atomic accumulators (rnk|gram contiguous = 16896 floats)
  zero_buf<<<(16896 + 255) / 256, 256, 0, stream>>>(rnk, 16896);

  // 1) split+transpose inputs, split weights
  cvt_split_T<<<dim3(Nb_ / 64, C_ / 64, B_), 256, 0, stream>>>(cf, XhK, XlK, Nb_);
  cvt_split_T<<<dim3(Ns_ / 64, C_ / 64, B_), 256, 0, stream>>>(x,  Xhx, Xlx, Ns_);
  cvt_w<<<3 * 65536 / 256, 256, 0, stream>>>(Wq, Wk, Wv, Wp);

  // 2) MFMA GEMMs: q single, k/v dual (N-tile 128)
  gemm_mfma<false><<<dim3(Ns_ / 128, C_ / 64, B_), 256, 0, stream>>>(
      Xhx, Xlx, Wp, Wp + 65536, nullptr, nullptr, A, nullptr, Ns_);
  gemm_mfma<true><<<dim3(Nb_ / 128, C_ / 64, B_), 256, 0, stream>>>(
      XhK, XlK, Wp + 131072, Wp + 196608, Wp + 262144, Wp + 327680, Bb, Cb, Nb_);

  // 3) fused wtconv: q (64x64), k (128x128, +norm fold), v (128x128)
  wtconv_fused<64><<<dim3(1, C_, B_), 256, 0, stream>>>(A, q_bw, q_bs, q_ww, q_ws, Fb, nullptr);
  wtconv_fused<128><<<dim3(4, C_, B_), 256, 0, stream>>>(Bb, k_bw, k_bs, k_ww, k_ws, Gb, rnk);
  wtconv_fused<128><<<dim3(4, C_, B_), 256, 0, stream>>>(Cb, v_bw, v_bs, v_ww, v_ws, Hb, nullptr);

  // 4) upsample q1 -> q_up (into Bb; k0 dead) + rnq direct
  resize2x_norm<<<B_ * C_, 256, 0, stream>>>(Fb, Bb, rnq);

  // 5) gram + softmax
  gram_qk<<<dim3(32, HEADS_, B_), 256, 0, stream>>>(Bb, Gb, gram);
  attn_softmax<<<dim3(HEADS_, B_), 1024, 0, stream>>>(gram, rnq, rnk, temp, attn);

  // 6) fused attn@v + proj -> d_out
  av_proj<<<dim3(Nb_ / 4 / 128, B_ * HEADS_), 256, 0, stream>>>(
      attn, Hb, p_bw, p_bs, p_ww, p_ws, (float*)d_out);
}